// Round 3
// baseline (329.027 us; speedup 1.0000x reference)
//
#include <hip/hip_runtime.h>

typedef unsigned short u16;
typedef __attribute__((ext_vector_type(4))) float f32x4;
typedef __attribute__((ext_vector_type(8))) short short8;

#define WIN_SZ 100
#define NWIN 41
#define NBATCH 8
#define SEQ 4096
#define DM 512
#define NHEAD 8
#define KD 64
#define NWINS (NBATCH * NWIN)    // 328
#define MROWS (NWINS * WIN_SZ)   // 32800
#define MBLKS 257                // ceil(32800/128)
#define TOKPB (NWIN * WIN_SZ)    // 4100
#define NQKV 1536

// ws layout (u16 element offsets)
#define OFF_XBF   0u
#define OFF_OBUF  16793600u                 // + MROWS*DM
#define OFF_WQKVT 33587200u                 // + MROWS*DM
#define OFF_WOT   34373632u                 // + NQKV*DM
#define OFF_ZBLK  34635776u                 // + DM*DM
#define OFF_BIAS  34636032u                 // + 256   (1536 fp32 qkv bias)
#define OFF_BIAS2 34639104u                 // + 3072  (512 fp32 bo)

__device__ __forceinline__ u16 f2bf(float f) {
  union { float f; unsigned i; } v; v.f = f;
  unsigned r = (v.i + 0x7fffu + ((v.i >> 16) & 1u)) >> 16;
  return (u16)r;
}

// async global->LDS, 16B per lane; lds base wave-uniform (HW adds lane*16)
__device__ __forceinline__ void gl2lds16(const void* g, void* lds) {
  __builtin_amdgcn_global_load_lds(
      (const __attribute__((address_space(1))) void*)g,
      (__attribute__((address_space(3))) void*)lds, 16, 0, 0);
}

// ---------- prep: LDS-tiled 64x64 transposes (coalesced) + biases + zblk ----------
// z=0..2: Wq/Wk/Wv -> WqkvT rows [z*512, z*512+512); z=3: Wo -> WoT.
__global__ void prep_k(const float* __restrict__ Wq, const float* __restrict__ Wk,
                       const float* __restrict__ Wv, const float* __restrict__ Wo,
                       const float* __restrict__ bq, const float* __restrict__ bk,
                       const float* __restrict__ bv, const float* __restrict__ bo,
                       u16* __restrict__ ws) {
  __shared__ u16 tile[64][65];
  const int z = blockIdx.z;
  const float* src = (z == 0) ? Wq : (z == 1) ? Wk : (z == 2) ? Wv : Wo;
  u16* dst = (z < 3) ? (ws + OFF_WQKVT + (unsigned)z * 512u * 512u)
                     : (ws + OFF_WOT);
  const int k0 = blockIdx.y * 64, n0 = blockIdx.x * 64;
  const int t = threadIdx.x;
  const int c = t & 63, r4 = t >> 6;
#pragma unroll
  for (int p = 0; p < 16; ++p) {
    int r = p * 4 + r4;
    tile[r][c] = f2bf(src[(size_t)(k0 + r) * 512 + n0 + c]);
  }
  __syncthreads();
#pragma unroll
  for (int p = 0; p < 16; ++p) {
    int r = p * 4 + r4;                       // n index within tile
    dst[(size_t)(n0 + r) * 512 + k0 + c] = tile[c][r];
  }
  if (blockIdx.x == 0 && blockIdx.y == 0) {
    float* biasF = (float*)(ws + OFF_BIAS);
    float* biasO = (float*)(ws + OFF_BIAS2);
    for (int j = t; j < 512; j += 256) {
      if (z == 0) biasF[j] = bq[j];
      else if (z == 1) biasF[512 + j] = bk[j];
      else if (z == 2) biasF[1024 + j] = bv[j];
      else biasO[j] = bo[j];
    }
    if (z == 3 && t < 128) ws[OFF_ZBLK + t] = 0;
  }
}

// ---------------- x fp32 -> bf16 with window-padding gather ----------------
__global__ void convx_k(const float* __restrict__ x, u16* __restrict__ ws) {
  u16* xbf = ws + OFF_XBF;
  int i = blockIdx.x * 256 + threadIdx.x;     // float4-group index
  if (i >= MROWS * 128) return;
  int m = i >> 7;
  int c4 = (i & 127) * 4;
  int b = m / TOKPB, tk = m - b * TOKPB;
  float4 v = make_float4(0.f, 0.f, 0.f, 0.f);
  if (tk < SEQ) v = *(const float4*)(x + (size_t)(b * SEQ + tk) * DM + c4);
  u16 o[4] = {f2bf(v.x), f2bf(v.y), f2bf(v.z), f2bf(v.w)};
  *(uint2*)(xbf + (size_t)m * DM + c4) = *(const uint2*)o;
}

// -------------- fused QKV projection + attention, one block per (win, head) --------------
#define QKS 72   // Qs/Ks stride
#define PS 136   // P / Vt stride
// LDS phase-union (u16 elems), total 24832 (49664 B -> 3 blocks/CU):
//   phase1 (staging, dies at post-loop barrier): dbuf b in {0,1}:
//     Xs_b [b*9728, b*9728+3584)  (112 x 32), Wsl_b [b*9728+3584, b*9728+9728) (192 x 32)
//   phase2+: Vt [0,8704) | Qs [8704,16768) | Ks [16768,24832)
//   phase4:  P  [8704,23936) overlays Qs+Ks
#define SM_ELEMS 24832
#define STG_BUF 9728   // u16 elems per staging buffer (Xs 3584 + Wsl 6144)

__global__ __launch_bounds__(256, 3)
void qkvattn_k(const u16* __restrict__ ws) {
  __shared__ u16 smem[SM_ELEMS];
  u16* Vt  = smem;              // 64 x 136
  u16* Qs  = smem + 8704;       // 112 x 72
  u16* Ks  = smem + 16768;      // 112 x 72
  u16* P   = smem + 8704;       // 112 x 136

  const int win = blockIdx.x, h = blockIdx.y;
  const int t = threadIdx.x, w = t >> 6, l = t & 63;
  const int q = l >> 4, cl = l & 15;

  // ---- staging descriptor: 19 gl2lds instrs per K-step (BK=32) ----
  // id 0..6:  X rows [id*16, id*16+16)   (row stride 32 u16 = 64B -> uniform 8-deep banks)
  // id 7..18: W rows [(id-7)*16, ...)
  // wave w owns ids {w, w+4, w+8, w+12, w+16} (wave 3: 4 ids)
  unsigned ssrc[5], smask[5], sdst[5];
  int cnt = 0;
#pragma unroll
  for (int j = 0; j < 5; ++j) {
    const int id = w + j * 4;
    if (id < 19) {
      if (id < 7) {
        const int m = id * 16 + (l >> 2);
        const bool real = (m < WIN_SZ);
        ssrc[cnt] = real ? (OFF_XBF + (unsigned)(win * WIN_SZ + m) * DM + (unsigned)(l & 3) * 8u)
                         : OFF_ZBLK;
        smask[cnt] = real ? 0xFFFFFFFFu : 0u;
        sdst[cnt] = (unsigned)id * 512u;
      } else {
        const int g = (id - 7) * 16 + (l >> 2);
        const unsigned nrow = (unsigned)(g >> 6) * 512u + (unsigned)h * 64u + (unsigned)(g & 63);
        ssrc[cnt] = OFF_WQKVT + nrow * DM + (unsigned)(l & 3) * 8u;
        smask[cnt] = 0xFFFFFFFFu;
        sdst[cnt] = 3584u + (unsigned)(id - 7) * 512u;
      }
      ++cnt;
    }
  }

  // ---- phase 1: QKV projection, single-barrier double-buffered pipeline ----
  // body(k): issue stage(k+1) -> buf^1; compute(k) from buf; __syncthreads()
  // (implicit vmcnt(0) drains the loads issued at the TOP of this iter, with the
  //  whole compute in between -> latency hidden; one barrier per K-step).
  f32x4 acc_p[7][3] = {};

  // prologue: stage k-step 0 into buf 0
#pragma unroll
  for (int j = 0; j < 5; ++j)
    if (j < cnt) gl2lds16(ws + ssrc[j], &smem[sdst[j]]);
  __syncthreads();

  for (int it = 0; it < 16; ++it) {
    const int cur = it & 1;
    if (it < 15) {
      const unsigned k0n = (unsigned)(it + 1) * 32u;
      const unsigned bb = (unsigned)(cur ^ 1) * STG_BUF;
#pragma unroll
      for (int j = 0; j < 5; ++j)
        if (j < cnt) gl2lds16(ws + ssrc[j] + (k0n & smask[j]), &smem[bb + sdst[j]]);
    }
    const u16* Xb = smem + cur * STG_BUF;
    const u16* Wb = Xb + 3584;
    const int ko = q * 8;
    short8 af[7], bf[3];
#pragma unroll
    for (int mt = 0; mt < 7; ++mt)
      af[mt] = *(const short8*)&Xb[(mt * 16 + cl) * 32 + ko];
#pragma unroll
    for (int ntl = 0; ntl < 3; ++ntl)
      bf[ntl] = *(const short8*)&Wb[((3 * w + ntl) * 16 + cl) * 32 + ko];
#pragma unroll
    for (int mt = 0; mt < 7; ++mt)
#pragma unroll
      for (int ntl = 0; ntl < 3; ++ntl)
        acc_p[mt][ntl] = __builtin_amdgcn_mfma_f32_16x16x32_bf16(
            af[mt], bf[ntl], acc_p[mt][ntl], 0, 0, 0);
    __syncthreads();
  }
  // final __syncthreads above also fences staging region before phase 2 reuse

  // ---- phase 2: accs (+bias) -> Qs / Ks / Vt ----
  {
    const float* biasF = (const float*)(ws + OFF_BIAS);
#pragma unroll
    for (int ntl = 0; ntl < 3; ++ntl) {
      const int nt = 3 * w + ntl;
      const int cw = (nt & 3) * 16 + cl;               // col within Q/K/V
      const float bb = biasF[(nt >> 2) * 512 + h * 64 + cw];
#pragma unroll
      for (int mt = 0; mt < 7; ++mt)
#pragma unroll
        for (int r = 0; r < 4; ++r) {
          const int tok = mt * 16 + q * 4 + r;
          const u16 v16 = f2bf(acc_p[mt][ntl][r] + bb);
          if (nt < 4) Qs[tok * QKS + cw] = v16;
          else if (nt < 8) Ks[tok * QKS + cw] = v16;
          else Vt[cw * PS + tok] = v16;
        }
    }
    for (int idx = t; idx < 64 * 24; idx += 256)       // Vt cols 112..135 = 0
      Vt[(idx / 24) * PS + 112 + idx % 24] = 0;
  }
  __syncthreads();

  // ---- phase 3: S = Q K^T. wave w owns m-tiles {w, w+4} (wave 3: {3}) ----
  const int nmt = (w < 3) ? 2 : 1;
  const int mt0 = w, mt1 = w + 4;

  f32x4 accs[2][7];
#pragma unroll
  for (int im = 0; im < 2; ++im) {
    if (im < nmt) {
      const int mt = (im == 0) ? mt0 : mt1;
      const int ar = (mt * 16 + cl) * QKS + q * 8;
      short8 a0 = *(const short8*)&Qs[ar];
      short8 a1 = *(const short8*)&Qs[ar + 32];
#pragma unroll
      for (int nt = 0; nt < 7; ++nt) {
        const int br = (nt * 16 + cl) * QKS + q * 8;
        short8 b0 = *(const short8*)&Ks[br];
        short8 b1 = *(const short8*)&Ks[br + 32];
        f32x4 c = {};
        c = __builtin_amdgcn_mfma_f32_16x16x32_bf16(a0, b0, c, 0, 0, 0);
        c = __builtin_amdgcn_mfma_f32_16x16x32_bf16(a1, b1, c, 0, 0, 0);
        accs[im][nt] = c;
      }
    }
  }

  // softmax over cols 0..99 (100..111 masked), in registers
  const float scale = 0.125f;  // 1/sqrt(64)
#pragma unroll
  for (int im = 0; im < 2; ++im) {
    if (im < nmt) {
#pragma unroll
      for (int r = 0; r < 4; ++r) {
        float mx = -1e30f;
#pragma unroll
        for (int nt = 0; nt < 7; ++nt) {
          float s = accs[im][nt][r] * scale;
          if ((nt < 6) || (cl < 4)) mx = fmaxf(mx, s);
        }
        mx = fmaxf(mx, __shfl_xor(mx, 1, 64));
        mx = fmaxf(mx, __shfl_xor(mx, 2, 64));
        mx = fmaxf(mx, __shfl_xor(mx, 4, 64));
        mx = fmaxf(mx, __shfl_xor(mx, 8, 64));
        float sum = 0.f;
#pragma unroll
        for (int nt = 0; nt < 7; ++nt) {
          float s = accs[im][nt][r] * scale;
          bool valid = (nt < 6) || (cl < 4);
          float e = valid ? __expf(s - mx) : 0.f;
          accs[im][nt][r] = e;
          sum += e;
        }
        sum += __shfl_xor(sum, 1, 64);
        sum += __shfl_xor(sum, 2, 64);
        sum += __shfl_xor(sum, 4, 64);
        sum += __shfl_xor(sum, 8, 64);
        float inv = 1.0f / sum;
#pragma unroll
        for (int nt = 0; nt < 7; ++nt) accs[im][nt][r] *= inv;
      }
    }
  }
  __syncthreads();  // Qs/Ks reads drained before P overwrites them

  // ---- phase 4: P write + PV ----
#pragma unroll
  for (int im = 0; im < 2; ++im) {
    if (im < nmt) {
      const int mt = (im == 0) ? mt0 : mt1;
#pragma unroll
      for (int nt = 0; nt < 7; ++nt)
#pragma unroll
        for (int r = 0; r < 4; ++r)
          P[(mt * 16 + q * 4 + r) * PS + nt * 16 + cl] = f2bf(accs[im][nt][r]);
    }
  }
  for (int idx = t; idx < 112 * 24; idx += 256)        // P cols 112..135 = 0
    P[(idx / 24) * PS + 112 + idx % 24] = 0;
  __syncthreads();

  f32x4 acco[2][4] = {};
#pragma unroll
  for (int ks = 0; ks < 4; ++ks) {
    const int ko = ks * 32 + q * 8;
    short8 a0 = *(const short8*)&P[(mt0 * 16 + cl) * PS + ko];
    short8 a1 = a0;
    if (nmt == 2) a1 = *(const short8*)&P[(mt1 * 16 + cl) * PS + ko];
#pragma unroll
    for (int nt = 0; nt < 4; ++nt) {
      short8 b = *(const short8*)&Vt[(nt * 16 + cl) * PS + ko];
      acco[0][nt] = __builtin_amdgcn_mfma_f32_16x16x32_bf16(a0, b, acco[0][nt], 0, 0, 0);
      if (nmt == 2)
        acco[1][nt] = __builtin_amdgcn_mfma_f32_16x16x32_bf16(a1, b, acco[1][nt], 0, 0, 0);
    }
  }

  u16* obuf = (u16*)(ws + OFF_OBUF);
  const size_t orow0 = (size_t)win * WIN_SZ;
#pragma unroll
  for (int im = 0; im < 2; ++im) {
    if (im < nmt) {
      const int mt = (im == 0) ? mt0 : mt1;
#pragma unroll
      for (int nt = 0; nt < 4; ++nt)
#pragma unroll
        for (int r = 0; r < 4; ++r) {
          int row = mt * 16 + q * 4 + r;
          if (row < WIN_SZ)
            obuf[(orow0 + row) * DM + h * KD + nt * 16 + cl] = f2bf(acco[im][nt][r]);
        }
    }
  }
}

// ---------------- GEMM: C[M,N] = A[M,512] @ Bt[N,512]^T + bias (fp32 out) ----------------
// Same single-barrier dbuf BK=32 pipeline as qkvattn_k phase 1.
__global__ __launch_bounds__(256, 4)
void gemm_k(const u16* __restrict__ ws, unsigned aoff0, unsigned btoff,
            unsigned biasoff, float* __restrict__ Cout, int Ntot) {
  __shared__ u16 smg[2][8192];   // buf b: A [0,4096) (128x32), B [4096,8192)

  const int t = threadIdx.x;
  const int w = t >> 6;
  const int l = t & 63;
  const int nb = blockIdx.x, mb = blockIdx.y;
  const int m0 = mb * 128, n0 = nb * 128;
  const int q = l >> 4, cl = l & 15;

  // staging: 16 instrs / K-step; wave w owns ids {w, w+4, w+8, w+12}
  unsigned ssrc[4], smask[4], sdst[4];
#pragma unroll
  for (int j = 0; j < 4; ++j) {
    const int id = w + j * 4;
    if (id < 8) {
      const int m = m0 + id * 16 + (l >> 2);
      const bool real = (m < MROWS);
      ssrc[j] = real ? (aoff0 + (unsigned)m * DM + (unsigned)(l & 3) * 8u) : OFF_ZBLK;
      smask[j] = real ? 0xFFFFFFFFu : 0u;
      sdst[j] = (unsigned)id * 512u;
    } else {
      const int n = n0 + (id - 8) * 16 + (l >> 2);
      ssrc[j] = btoff + (unsigned)n * DM + (unsigned)(l & 3) * 8u;
      smask[j] = 0xFFFFFFFFu;
      sdst[j] = 4096u + (unsigned)(id - 8) * 512u;
    }
  }

  f32x4 acc[4][4] = {};
  const int wm = (w & 1) * 64;
  const int wn = (w >> 1) * 64;

  // prologue
#pragma unroll
  for (int j = 0; j < 4; ++j) gl2lds16(ws + ssrc[j], &smg[0][sdst[j]]);
  __syncthreads();

  for (int it = 0; it < 16; ++it) {
    const int cur = it & 1;
    if (it < 15) {
      const unsigned k0n = (unsigned)(it + 1) * 32u;
#pragma unroll
      for (int j = 0; j < 4; ++j)
        gl2lds16(ws + ssrc[j] + (k0n & smask[j]), &smg[cur ^ 1][sdst[j]]);
    }
    const u16* Ab = smg[cur];
    const u16* Bb = Ab + 4096;
    const int ko = q * 8;
    short8 av[4], bv_[4];
#pragma unroll
    for (int mi = 0; mi < 4; ++mi)
      av[mi] = *(const short8*)&Ab[(wm + mi * 16 + cl) * 32 + ko];
#pragma unroll
    for (int ni = 0; ni < 4; ++ni)
      bv_[ni] = *(const short8*)&Bb[(wn + ni * 16 + cl) * 32 + ko];
#pragma unroll
    for (int mi = 0; mi < 4; ++mi)
#pragma unroll
      for (int ni = 0; ni < 4; ++ni)
        acc[mi][ni] = __builtin_amdgcn_mfma_f32_16x16x32_bf16(
            av[mi], bv_[ni], acc[mi][ni], 0, 0, 0);
    __syncthreads();
  }

  const float* biasF = (const float*)(ws + biasoff);
#pragma unroll
  for (int mi = 0; mi < 4; ++mi) {
#pragma unroll
    for (int ni = 0; ni < 4; ++ni) {
      int col = n0 + wn + ni * 16 + cl;
      float bb = biasF[col];
#pragma unroll
      for (int r = 0; r < 4; ++r) {
        int row = m0 + wm + mi * 16 + q * 4 + r;
        if (row < MROWS)
          Cout[(size_t)row * Ntot + col] = acc[mi][ni][r] + bb;
      }
    }
  }
}

extern "C" void kernel_launch(void* const* d_in, const int* in_sizes, int n_in,
                              void* d_out, int out_size, void* d_ws, size_t ws_size,
                              hipStream_t stream) {
  const float* x  = (const float*)d_in[0];
  const float* Wq = (const float*)d_in[1];
  const float* bq = (const float*)d_in[2];
  const float* Wk = (const float*)d_in[3];
  const float* bk = (const float*)d_in[4];
  const float* Wv = (const float*)d_in[5];
  const float* bv = (const float*)d_in[6];
  const float* Wo = (const float*)d_in[7];
  const float* bo = (const float*)d_in[8];

  u16* ws = (u16*)d_ws;

  prep_k<<<dim3(8, 8, 4), dim3(256), 0, stream>>>(
      Wq, Wk, Wv, Wo, bq, bk, bv, bo, ws);
  convx_k<<<dim3((MROWS * 128 + 255) / 256), dim3(256), 0, stream>>>(x, ws);
  qkvattn_k<<<dim3(NWINS, NHEAD), dim3(256), 0, stream>>>(ws);
  gemm_k<<<dim3(DM / 128, MBLKS), dim3(256), 0, stream>>>(
      ws, OFF_OBUF, OFF_WOT, OFF_BIAS2, (float*)d_out, DM);
}

// Round 4
// 287.168 us; speedup vs baseline: 1.1458x; 1.1458x over previous
//
#include <hip/hip_runtime.h>

typedef unsigned short u16;
typedef __attribute__((ext_vector_type(4))) float f32x4;
typedef __attribute__((ext_vector_type(8))) short short8;

#define WIN_SZ 100
#define NWIN 41
#define NBATCH 8
#define SEQ 4096
#define DM 512
#define NHEAD 8
#define KD 64
#define NWINS (NBATCH * NWIN)    // 328
#define MROWS (NWINS * WIN_SZ)   // 32800
#define MBLKS 257                // ceil(32800/128)
#define TOKPB (NWIN * WIN_SZ)    // 4100
#define NQKV 1536

// ws layout (u16 element offsets)
#define OFF_XBF   0u
#define OFF_OBUF  16793600u                 // + MROWS*DM
#define OFF_WQKVT 33587200u                 // + MROWS*DM
#define OFF_WOT   34373632u                 // + NQKV*DM
#define OFF_ZBLK  34635776u                 // + DM*DM
#define OFF_BIAS  34636032u                 // + 256   (1536 fp32 qkv bias)
#define OFF_BIAS2 34639104u                 // + 3072  (512 fp32 bo)

__device__ __forceinline__ u16 f2bf(float f) {
  union { float f; unsigned i; } v; v.f = f;
  unsigned r = (v.i + 0x7fffu + ((v.i >> 16) & 1u)) >> 16;
  return (u16)r;
}

// async global->LDS, 16B per lane; lds base wave-uniform (HW adds lane*16)
__device__ __forceinline__ void gl2lds16(const void* g, void* lds) {
  __builtin_amdgcn_global_load_lds(
      (const __attribute__((address_space(1))) void*)g,
      (__attribute__((address_space(3))) void*)lds, 16, 0, 0);
}

// ---------- prep: LDS-tiled 64x64 transposes (coalesced) + biases + zblk ----------
// z=0..2: Wq/Wk/Wv -> WqkvT rows [z*512, z*512+512); z=3: Wo -> WoT.
__global__ void prep_k(const float* __restrict__ Wq, const float* __restrict__ Wk,
                       const float* __restrict__ Wv, const float* __restrict__ Wo,
                       const float* __restrict__ bq, const float* __restrict__ bk,
                       const float* __restrict__ bv, const float* __restrict__ bo,
                       u16* __restrict__ ws) {
  __shared__ u16 tile[64][65];
  const int z = blockIdx.z;
  const float* src = (z == 0) ? Wq : (z == 1) ? Wk : (z == 2) ? Wv : Wo;
  u16* dst = (z < 3) ? (ws + OFF_WQKVT + (unsigned)z * 512u * 512u)
                     : (ws + OFF_WOT);
  const int k0 = blockIdx.y * 64, n0 = blockIdx.x * 64;
  const int t = threadIdx.x;
  const int c = t & 63, r4 = t >> 6;
#pragma unroll
  for (int p = 0; p < 16; ++p) {
    int r = p * 4 + r4;
    tile[r][c] = f2bf(src[(size_t)(k0 + r) * 512 + n0 + c]);
  }
  __syncthreads();
#pragma unroll
  for (int p = 0; p < 16; ++p) {
    int r = p * 4 + r4;                       // n index within tile
    dst[(size_t)(n0 + r) * 512 + k0 + c] = tile[c][r];
  }
  if (blockIdx.x == 0 && blockIdx.y == 0) {
    float* biasF = (float*)(ws + OFF_BIAS);
    float* biasO = (float*)(ws + OFF_BIAS2);
    for (int j = t; j < 512; j += 256) {
      if (z == 0) biasF[j] = bq[j];
      else if (z == 1) biasF[512 + j] = bk[j];
      else if (z == 2) biasF[1024 + j] = bv[j];
      else biasO[j] = bo[j];
    }
    if (z == 3 && t < 128) ws[OFF_ZBLK + t] = 0;
  }
}

// ---------------- x fp32 -> bf16 with window-padding gather ----------------
__global__ void convx_k(const float* __restrict__ x, u16* __restrict__ ws) {
  u16* xbf = ws + OFF_XBF;
  int i = blockIdx.x * 256 + threadIdx.x;     // float4-group index
  if (i >= MROWS * 128) return;
  int m = i >> 7;
  int c4 = (i & 127) * 4;
  int b = m / TOKPB, tk = m - b * TOKPB;
  float4 v = make_float4(0.f, 0.f, 0.f, 0.f);
  if (tk < SEQ) v = *(const float4*)(x + (size_t)(b * SEQ + tk) * DM + c4);
  u16 o[4] = {f2bf(v.x), f2bf(v.y), f2bf(v.z), f2bf(v.w)};
  *(uint2*)(xbf + (size_t)m * DM + c4) = *(const uint2*)o;
}

// -------------- fused QKV projection + attention, one block per (win, head) --------------
#define QKS 72   // Qs/Ks stride
#define PS 136   // P / Vt stride
// LDS (u16 elems), total 38912 (77824 B -> 2 blocks/CU):
//   phase1 staging, double-buffered (dies at the last phase-1 barrier):
//     buf b in {0,1} at b*19456: Xs [0,7168) 112x64, Wsl [7168,19456) 192x64
//   phase2+ overlays [0,24832): Vt [0,8704) | Qs [8704,16768) | Ks [16768,24832)
//   phase4:  P [8704,23936) overlays Qs+Ks
#define SM_ELEMS 38912
#define STG_BUF 19456

__global__ __launch_bounds__(256, 2)
void qkvattn_k(const u16* __restrict__ ws) {
  __shared__ u16 smem[SM_ELEMS];
  u16* Vt  = smem;              // 64 x 136
  u16* Qs  = smem + 8704;       // 112 x 72
  u16* Ks  = smem + 16768;      // 112 x 72
  u16* P   = smem + 8704;       // 112 x 136

  const int win = blockIdx.x, h = blockIdx.y;
  const int t = threadIdx.x, w = t >> 6, l = t & 63;
  const int q = l >> 4, cl = l & 15;
  // Bank-conflict fix (G4/T2, m173 pattern): global_load_lds writes LDS
  // linearly (row = base + lane>>3, slot = lane&7, 16B slots). Pre-swizzle
  // the GLOBAL source column so LDS slot s of row m holds global slot
  // s ^ (m&7); reads then XOR the slot with (row&7). Row-stride is 128 B
  // (= 32 banks), so unswizzled b128 reads would be 16-way conflicted.
  const int lsw = (((t & 7) ^ ((t >> 3) & 7)) * 8);

  // staging source offsets (column pre-swizzled), BK=64
  unsigned xoff[4];
#pragma unroll
  for (int i = 0; i < 4; ++i) {
    int m = i * 32 + (t >> 3);
    xoff[i] = (m < WIN_SZ)
                  ? (OFF_XBF + (unsigned)(win * WIN_SZ + m) * DM + lsw)
                  : OFF_ZBLK;
  }
  unsigned woff[6];
#pragma unroll
  for (int i = 0; i < 6; ++i) {
    int g = i * 32 + (t >> 3);
    unsigned nrow = (unsigned)(g >> 6) * 512u + (unsigned)h * 64u + (g & 63);
    woff[i] = OFF_WQKVT + nrow * DM + lsw;
  }

  // ---- phase 1: QKV projection, single-barrier double-buffered, BK=64 ----
  // iter k: issue stage(k+1)->buf^1; compute(k) from buf (42 MFMA + 20 b128,
  // ~450+ cyc covering the load latency); barrier (implicit vmcnt(0) drains
  // stage(k+1), lgkmcnt(0) drains reads of buf, so buf may be overwritten
  // next iter and buf^1 is ready). One barrier per K-step.
  f32x4 acc_p[7][3] = {};

  // prologue: stage k0=0 into buf 0
#pragma unroll
  for (int i = 0; i < 4; ++i)
    if (i * 32 + w * 8 < 112)   // wave-uniform
      gl2lds16(ws + xoff[i], &smem[(i * 32 + w * 8) * 64]);
#pragma unroll
  for (int i = 0; i < 6; ++i)
    gl2lds16(ws + woff[i], &smem[7168 + (i * 32 + w * 8) * 64]);
  __syncthreads();

  for (int it = 0; it < 8; ++it) {
    const int cur = it & 1;
    if (it < 7) {
      const unsigned k0n = (unsigned)(it + 1) * 64u;
      const unsigned bb = (unsigned)(cur ^ 1) * STG_BUF;
#pragma unroll
      for (int i = 0; i < 4; ++i)
        if (i * 32 + w * 8 < 112)   // wave-uniform
          gl2lds16(ws + xoff[i] + (xoff[i] == OFF_ZBLK ? 0u : k0n),
                   &smem[bb + (i * 32 + w * 8) * 64]);
#pragma unroll
      for (int i = 0; i < 6; ++i)
        gl2lds16(ws + woff[i] + k0n, &smem[bb + 7168 + (i * 32 + w * 8) * 64]);
    }
    const u16* Xb = smem + cur * STG_BUF;
    const u16* Wb = Xb + 7168;
#pragma unroll
    for (int ks = 0; ks < 2; ++ks) {
      const int ko = ks * 32 + q * 8;
      const int koS = ko ^ ((cl & 7) << 3);   // read-side swizzle
      short8 af[7], bf[3];
#pragma unroll
      for (int mt = 0; mt < 7; ++mt)
        af[mt] = *(const short8*)&Xb[(mt * 16 + cl) * 64 + koS];
#pragma unroll
      for (int ntl = 0; ntl < 3; ++ntl)
        bf[ntl] = *(const short8*)&Wb[((3 * w + ntl) * 16 + cl) * 64 + koS];
#pragma unroll
      for (int mt = 0; mt < 7; ++mt)
#pragma unroll
        for (int ntl = 0; ntl < 3; ++ntl)
          acc_p[mt][ntl] = __builtin_amdgcn_mfma_f32_16x16x32_bf16(
              af[mt], bf[ntl], acc_p[mt][ntl], 0, 0, 0);
    }
    __syncthreads();
  }
  // final barrier above: staging dead; Vt/Qs/Ks may now overwrite

  // ---- phase 2: accs (+bias) -> Qs / Ks / Vt ----
  {
    const float* biasF = (const float*)(ws + OFF_BIAS);
#pragma unroll
    for (int ntl = 0; ntl < 3; ++ntl) {
      const int nt = 3 * w + ntl;
      const int cw = (nt & 3) * 16 + cl;               // col within Q/K/V
      const float bb = biasF[(nt >> 2) * 512 + h * 64 + cw];
#pragma unroll
      for (int mt = 0; mt < 7; ++mt)
#pragma unroll
        for (int r = 0; r < 4; ++r) {
          const int tok = mt * 16 + q * 4 + r;
          const u16 v16 = f2bf(acc_p[mt][ntl][r] + bb);
          if (nt < 4) Qs[tok * QKS + cw] = v16;
          else if (nt < 8) Ks[tok * QKS + cw] = v16;
          else Vt[cw * PS + tok] = v16;
        }
    }
    for (int idx = t; idx < 64 * 24; idx += 256)       // Vt cols 112..135 = 0
      Vt[(idx / 24) * PS + 112 + idx % 24] = 0;
  }
  __syncthreads();

  // ---- phase 3: S = Q K^T. wave w owns m-tiles {w, w+4} (wave 3: {3}) ----
  const int nmt = (w < 3) ? 2 : 1;
  const int mt0 = w, mt1 = w + 4;

  f32x4 accs[2][7];
#pragma unroll
  for (int im = 0; im < 2; ++im) {
    if (im < nmt) {
      const int mt = (im == 0) ? mt0 : mt1;
      const int ar = (mt * 16 + cl) * QKS + q * 8;
      short8 a0 = *(const short8*)&Qs[ar];
      short8 a1 = *(const short8*)&Qs[ar + 32];
#pragma unroll
      for (int nt = 0; nt < 7; ++nt) {
        const int br = (nt * 16 + cl) * QKS + q * 8;
        short8 b0 = *(const short8*)&Ks[br];
        short8 b1 = *(const short8*)&Ks[br + 32];
        f32x4 c = {};
        c = __builtin_amdgcn_mfma_f32_16x16x32_bf16(a0, b0, c, 0, 0, 0);
        c = __builtin_amdgcn_mfma_f32_16x16x32_bf16(a1, b1, c, 0, 0, 0);
        accs[im][nt] = c;
      }
    }
  }

  // softmax over cols 0..99 (100..111 masked), in registers
  const float scale = 0.125f;  // 1/sqrt(64)
#pragma unroll
  for (int im = 0; im < 2; ++im) {
    if (im < nmt) {
#pragma unroll
      for (int r = 0; r < 4; ++r) {
        float mx = -1e30f;
#pragma unroll
        for (int nt = 0; nt < 7; ++nt) {
          float s = accs[im][nt][r] * scale;
          if ((nt < 6) || (cl < 4)) mx = fmaxf(mx, s);
        }
        mx = fmaxf(mx, __shfl_xor(mx, 1, 64));
        mx = fmaxf(mx, __shfl_xor(mx, 2, 64));
        mx = fmaxf(mx, __shfl_xor(mx, 4, 64));
        mx = fmaxf(mx, __shfl_xor(mx, 8, 64));
        float sum = 0.f;
#pragma unroll
        for (int nt = 0; nt < 7; ++nt) {
          float s = accs[im][nt][r] * scale;
          bool valid = (nt < 6) || (cl < 4);
          float e = valid ? __expf(s - mx) : 0.f;
          accs[im][nt][r] = e;
          sum += e;
        }
        sum += __shfl_xor(sum, 1, 64);
        sum += __shfl_xor(sum, 2, 64);
        sum += __shfl_xor(sum, 4, 64);
        sum += __shfl_xor(sum, 8, 64);
        float inv = 1.0f / sum;
#pragma unroll
        for (int nt = 0; nt < 7; ++nt) accs[im][nt][r] *= inv;
      }
    }
  }
  __syncthreads();  // Qs/Ks reads drained before P overwrites them

  // ---- phase 4: P write + PV ----
#pragma unroll
  for (int im = 0; im < 2; ++im) {
    if (im < nmt) {
      const int mt = (im == 0) ? mt0 : mt1;
#pragma unroll
      for (int nt = 0; nt < 7; ++nt)
#pragma unroll
        for (int r = 0; r < 4; ++r)
          P[(mt * 16 + q * 4 + r) * PS + nt * 16 + cl] = f2bf(accs[im][nt][r]);
    }
  }
  for (int idx = t; idx < 112 * 24; idx += 256)        // P cols 112..135 = 0
    P[(idx / 24) * PS + 112 + idx % 24] = 0;
  __syncthreads();

  f32x4 acco[2][4] = {};
#pragma unroll
  for (int ks = 0; ks < 4; ++ks) {
    const int ko = ks * 32 + q * 8;
    short8 a0 = *(const short8*)&P[(mt0 * 16 + cl) * PS + ko];
    short8 a1 = a0;
    if (nmt == 2) a1 = *(const short8*)&P[(mt1 * 16 + cl) * PS + ko];
#pragma unroll
    for (int nt = 0; nt < 4; ++nt) {
      short8 b = *(const short8*)&Vt[(nt * 16 + cl) * PS + ko];
      acco[0][nt] = __builtin_amdgcn_mfma_f32_16x16x32_bf16(a0, b, acco[0][nt], 0, 0, 0);
      if (nmt == 2)
        acco[1][nt] = __builtin_amdgcn_mfma_f32_16x16x32_bf16(a1, b, acco[1][nt], 0, 0, 0);
    }
  }

  u16* obuf = (u16*)(ws + OFF_OBUF);
  const size_t orow0 = (size_t)win * WIN_SZ;
#pragma unroll
  for (int im = 0; im < 2; ++im) {
    if (im < nmt) {
      const int mt = (im == 0) ? mt0 : mt1;
#pragma unroll
      for (int nt = 0; nt < 4; ++nt)
#pragma unroll
        for (int r = 0; r < 4; ++r) {
          int row = mt * 16 + q * 4 + r;
          if (row < WIN_SZ)
            obuf[(orow0 + row) * DM + h * KD + nt * 16 + cl] = f2bf(acco[im][nt][r]);
        }
    }
  }
}

// ---------------- GEMM: C[M,N] = A[M,512] @ Bt[N,512]^T + bias (fp32 out) ----------------
__global__ __launch_bounds__(256, 4)
void gemm_k(const u16* __restrict__ ws, unsigned aoff0, unsigned btoff,
            unsigned biasoff, float* __restrict__ Cout, int Ntot) {
  __shared__ u16 Alds[128 * 64];
  __shared__ u16 Blds[128 * 64];

  const int t = threadIdx.x;
  const int w = t >> 6;
  const int l = t & 63;
  const int nb = blockIdx.x, mb = blockIdx.y;
  const int m0 = mb * 128, n0 = nb * 128;
  const int lr = t >> 3;
  // same G4/T2 swizzle as qkvattn_k phase 1 (128B row stride)
  const int lsw = (((t & 7) ^ ((t >> 3) & 7)) * 8);

  unsigned aoff[4], boff[4];
#pragma unroll
  for (int i = 0; i < 4; ++i) {
    int m = m0 + i * 32 + lr;
    aoff[i] = (m < MROWS) ? (aoff0 + (unsigned)m * DM + lsw) : OFF_ZBLK;
    boff[i] = btoff + (unsigned)(n0 + i * 32 + lr) * DM + lsw;
  }

  f32x4 acc[4][4] = {};
  const int wm = (w & 1) * 64;
  const int wn = (w >> 1) * 64;
  const int q = l >> 4, cl = l & 15;

  for (int k0 = 0; k0 < DM; k0 += 64) {
    __syncthreads();
#pragma unroll
    for (int i = 0; i < 4; ++i) {
      gl2lds16(ws + aoff[i] + (aoff[i] == OFF_ZBLK ? 0u : (unsigned)k0),
               &Alds[(i * 32 + w * 8) * 64]);
      gl2lds16(ws + boff[i] + k0, &Blds[(i * 32 + w * 8) * 64]);
    }
    __syncthreads();
#pragma unroll
    for (int ks = 0; ks < 2; ++ks) {
      short8 av[4], bv_[4];
      const int ko = ks * 32 + q * 8;
      const int koS = ko ^ ((cl & 7) << 3);   // read-side swizzle
#pragma unroll
      for (int mi = 0; mi < 4; ++mi)
        av[mi] = *(const short8*)&Alds[(wm + mi * 16 + cl) * 64 + koS];
#pragma unroll
      for (int ni = 0; ni < 4; ++ni)
        bv_[ni] = *(const short8*)&Blds[(wn + ni * 16 + cl) * 64 + koS];
#pragma unroll
      for (int mi = 0; mi < 4; ++mi)
#pragma unroll
        for (int ni = 0; ni < 4; ++ni)
          acc[mi][ni] = __builtin_amdgcn_mfma_f32_16x16x32_bf16(
              av[mi], bv_[ni], acc[mi][ni], 0, 0, 0);
    }
  }

  const float* biasF = (const float*)(ws + biasoff);
#pragma unroll
  for (int mi = 0; mi < 4; ++mi) {
#pragma unroll
    for (int ni = 0; ni < 4; ++ni) {
      int col = n0 + wn + ni * 16 + cl;
      float bb = biasF[col];
#pragma unroll
      for (int r = 0; r < 4; ++r) {
        int row = m0 + wm + mi * 16 + q * 4 + r;
        if (row < MROWS)
          Cout[(size_t)row * Ntot + col] = acc[mi][ni][r] + bb;
      }
    }
  }
}

extern "C" void kernel_launch(void* const* d_in, const int* in_sizes, int n_in,
                              void* d_out, int out_size, void* d_ws, size_t ws_size,
                              hipStream_t stream) {
  const float* x  = (const float*)d_in[0];
  const float* Wq = (const float*)d_in[1];
  const float* bq = (const float*)d_in[2];
  const float* Wk = (const float*)d_in[3];
  const float* bk = (const float*)d_in[4];
  const float* Wv = (const float*)d_in[5];
  const float* bv = (const float*)d_in[6];
  const float* Wo = (const float*)d_in[7];
  const float* bo = (const float*)d_in[8];

  u16* ws = (u16*)d_ws;

  prep_k<<<dim3(8, 8, 4), dim3(256), 0, stream>>>(
      Wq, Wk, Wv, Wo, bq, bk, bv, bo, ws);
  convx_k<<<dim3((MROWS * 128 + 255) / 256), dim3(256), 0, stream>>>(x, ws);
  qkvattn_k<<<dim3(NWINS, NHEAD), dim3(256), 0, stream>>>(ws);
  gemm_k<<<dim3(DM / 128, MBLKS), dim3(256), 0, stream>>>(
      ws, OFF_OBUF, OFF_WOT, OFF_BIAS2, (float*)d_out, DM);
}

// Round 5
// 248.973 us; speedup vs baseline: 1.3215x; 1.1534x over previous
//
#include <hip/hip_runtime.h>

typedef unsigned short u16;
typedef __attribute__((ext_vector_type(4))) float f32x4;
typedef __attribute__((ext_vector_type(8))) short short8;

#define WIN_SZ 100
#define NWIN 41
#define NBATCH 8
#define SEQ 4096
#define DM 512
#define NHEAD 8
#define KD 64
#define NWINS (NBATCH * NWIN)    // 328
#define MROWS (NWINS * WIN_SZ)   // 32800
#define MBLKS 257                // ceil(32800/128)
#define TOKPB (NWIN * WIN_SZ)    // 4100
#define NQKV 1536

// ws layout (u16 element offsets)
#define OFF_XBF   0u
#define OFF_OBUF  16793600u                 // + MROWS*DM
#define OFF_WQKVT 33587200u                 // + MROWS*DM
#define OFF_WOT   34373632u                 // + NQKV*DM
#define OFF_ZBLK  34635776u                 // + DM*DM
#define OFF_BIAS  34636032u                 // + 256   (1536 fp32 qkv bias)
#define OFF_BIAS2 34639104u                 // + 3072  (512 fp32 bo)

__device__ __forceinline__ u16 f2bf(float f) {
  union { float f; unsigned i; } v; v.f = f;
  unsigned r = (v.i + 0x7fffu + ((v.i >> 16) & 1u)) >> 16;
  return (u16)r;
}

// async global->LDS, 16B per lane; lds base wave-uniform (HW adds lane*16)
__device__ __forceinline__ void gl2lds16(const void* g, void* lds) {
  __builtin_amdgcn_global_load_lds(
      (const __attribute__((address_space(1))) void*)g,
      (__attribute__((address_space(3))) void*)lds, 16, 0, 0);
}

// ---------- prep: LDS-tiled 64x64 transposes (coalesced) + biases + zblk ----------
// z=0..2: Wq/Wk/Wv -> WqkvT rows [z*512, z*512+512); z=3: Wo -> WoT.
__global__ void prep_k(const float* __restrict__ Wq, const float* __restrict__ Wk,
                       const float* __restrict__ Wv, const float* __restrict__ Wo,
                       const float* __restrict__ bq, const float* __restrict__ bk,
                       const float* __restrict__ bv, const float* __restrict__ bo,
                       u16* __restrict__ ws) {
  __shared__ u16 tile[64][65];
  const int z = blockIdx.z;
  const float* src = (z == 0) ? Wq : (z == 1) ? Wk : (z == 2) ? Wv : Wo;
  u16* dst = (z < 3) ? (ws + OFF_WQKVT + (unsigned)z * 512u * 512u)
                     : (ws + OFF_WOT);
  const int k0 = blockIdx.y * 64, n0 = blockIdx.x * 64;
  const int t = threadIdx.x;
  const int c = t & 63, r4 = t >> 6;
#pragma unroll
  for (int p = 0; p < 16; ++p) {
    int r = p * 4 + r4;
    tile[r][c] = f2bf(src[(size_t)(k0 + r) * 512 + n0 + c]);
  }
  __syncthreads();
#pragma unroll
  for (int p = 0; p < 16; ++p) {
    int r = p * 4 + r4;                       // n index within tile
    dst[(size_t)(n0 + r) * 512 + k0 + c] = tile[c][r];
  }
  if (blockIdx.x == 0 && blockIdx.y == 0) {
    float* biasF = (float*)(ws + OFF_BIAS);
    float* biasO = (float*)(ws + OFF_BIAS2);
    for (int j = t; j < 512; j += 256) {
      if (z == 0) biasF[j] = bq[j];
      else if (z == 1) biasF[512 + j] = bk[j];
      else if (z == 2) biasF[1024 + j] = bv[j];
      else biasO[j] = bo[j];
    }
    if (z == 3 && t < 128) ws[OFF_ZBLK + t] = 0;
  }
}

// ---------------- x fp32 -> bf16 with window-padding gather ----------------
__global__ void convx_k(const float* __restrict__ x, u16* __restrict__ ws) {
  u16* xbf = ws + OFF_XBF;
  int i = blockIdx.x * 256 + threadIdx.x;     // float4-group index
  if (i >= MROWS * 128) return;
  int m = i >> 7;
  int c4 = (i & 127) * 4;
  int b = m / TOKPB, tk = m - b * TOKPB;
  float4 v = make_float4(0.f, 0.f, 0.f, 0.f);
  if (tk < SEQ) v = *(const float4*)(x + (size_t)(b * SEQ + tk) * DM + c4);
  u16 o[4] = {f2bf(v.x), f2bf(v.y), f2bf(v.z), f2bf(v.w)};
  *(uint2*)(xbf + (size_t)m * DM + c4) = *(const uint2*)o;
}

// -------------- fused QKV projection + attention, one block per (win, head) --------------
#define QKS 72   // Qs/Ks stride
#define PS 136   // P / Vt stride
// LDS phase-union (u16 elems), total 24832 (49664 B -> 3 blocks/CU):
//   phase1 (staging, dies at post-loop barrier): Xs [0,7168) + Wsl [7168,19456)
//   phase2+: Vt [0,8704) | Qs [8704,16768) | Ks [16768,24832)
//   phase4:  P  [8704,23936) overlays Qs+Ks
#define SM_ELEMS 24832

__global__ __launch_bounds__(256, 3)
void qkvattn_k(const u16* __restrict__ ws) {
  __shared__ u16 smem[SM_ELEMS];
  u16* Xs  = smem;              // 112 x 64 (column-slot XOR-swizzled per row)
  u16* Wsl = smem + 7168;       // 192 x 64 (column-slot XOR-swizzled per row)
  u16* Vt  = smem;              // 64 x 136
  u16* Qs  = smem + 8704;       // 112 x 72
  u16* Ks  = smem + 16768;      // 112 x 72
  u16* P   = smem + 8704;       // 112 x 136

  const int win = blockIdx.x, h = blockIdx.y;
  const int t = threadIdx.x, w = t >> 6, l = t & 63;
  const int q = l >> 4, cl = l & 15;
  // Bank-conflict fix (G4/T2, m173 pattern): global_load_lds writes LDS
  // linearly (row = base + lane>>3, slot = lane&7, 16B slots). Pre-swizzle
  // the GLOBAL source column so LDS slot s of row m holds global slot
  // s ^ (m&7); reads then XOR the slot with (row&7). Row-stride is 128 B
  // (= 32 banks), so unswizzled b128 reads were 16-way conflicted.
  const int lsw = (((t & 7) ^ ((t >> 3) & 7)) * 8);

  // staging source offsets (column pre-swizzled)
  unsigned xoff[4];
#pragma unroll
  for (int i = 0; i < 4; ++i) {
    int m = i * 32 + (t >> 3);
    xoff[i] = (m < WIN_SZ)
                  ? (OFF_XBF + (unsigned)(win * WIN_SZ + m) * DM + lsw)
                  : OFF_ZBLK;
  }
  unsigned woff[6];
#pragma unroll
  for (int i = 0; i < 6; ++i) {
    int g = i * 32 + (t >> 3);
    unsigned nrow = (unsigned)(g >> 6) * 512u + (unsigned)h * 64u + (g & 63);
    woff[i] = OFF_WQKVT + nrow * DM + lsw;
  }

  // ---- phase 1: QKV projection. wave w owns n-tiles {3w,3w+1,3w+2} of 12 ----
  f32x4 acc_p[7][3] = {};
  for (int k0 = 0; k0 < DM; k0 += 64) {
    __syncthreads();
#pragma unroll
    for (int i = 0; i < 4; ++i)
      if (i * 32 + w * 8 < 112)   // wave-uniform
        gl2lds16(ws + xoff[i] + (xoff[i] == OFF_ZBLK ? 0u : (unsigned)k0),
                 &Xs[(i * 32 + w * 8) * 64]);
#pragma unroll
    for (int i = 0; i < 6; ++i)
      gl2lds16(ws + woff[i] + k0, &Wsl[(i * 32 + w * 8) * 64]);
    __syncthreads();
#pragma unroll
    for (int ks = 0; ks < 2; ++ks) {
      const int ko = ks * 32 + q * 8;
      const int koS = ko ^ ((cl & 7) << 3);   // read-side swizzle
      short8 af[7], bf[3];
#pragma unroll
      for (int mt = 0; mt < 7; ++mt)
        af[mt] = *(const short8*)&Xs[(mt * 16 + cl) * 64 + koS];
#pragma unroll
      for (int ntl = 0; ntl < 3; ++ntl)
        bf[ntl] = *(const short8*)&Wsl[((3 * w + ntl) * 16 + cl) * 64 + koS];
      __builtin_amdgcn_s_setprio(1);
#pragma unroll
      for (int mt = 0; mt < 7; ++mt)
#pragma unroll
        for (int ntl = 0; ntl < 3; ++ntl)
          acc_p[mt][ntl] = __builtin_amdgcn_mfma_f32_16x16x32_bf16(
              af[mt], bf[ntl], acc_p[mt][ntl], 0, 0, 0);
      __builtin_amdgcn_s_setprio(0);
    }
  }
  __syncthreads();  // staging reads drained; Vt/Qs/Ks may now overwrite

  // ---- phase 2: accs (+bias) -> Qs / Ks / Vt ----
  {
    const float* biasF = (const float*)(ws + OFF_BIAS);
#pragma unroll
    for (int ntl = 0; ntl < 3; ++ntl) {
      const int nt = 3 * w + ntl;                      // wave-uniform
      const int cw = (nt & 3) * 16 + cl;               // col within Q/K/V
      const float bb = biasF[(nt >> 2) * 512 + h * 64 + cw];
      if (nt < 8) {
        u16* dst = (nt < 4) ? Qs : Ks;
#pragma unroll
        for (int mt = 0; mt < 7; ++mt)
#pragma unroll
          for (int r = 0; r < 4; ++r) {
            const int tok = mt * 16 + q * 4 + r;
            dst[tok * QKS + cw] = f2bf(acc_p[mt][ntl][r] + bb);
          }
      } else {
        // V: r-index is contiguous in Vt -> pack 4 u16 into one b64 write
#pragma unroll
        for (int mt = 0; mt < 7; ++mt) {
          u16 pk[4];
#pragma unroll
          for (int r = 0; r < 4; ++r) pk[r] = f2bf(acc_p[mt][ntl][r] + bb);
          *(uint2*)&Vt[cw * PS + mt * 16 + q * 4] = *(const uint2*)pk;
        }
      }
    }
    // zero Vt pad cols 112..127 (PV ks=3 reads up to col 127): 64 rows x 4 b64
    {
      const int row = t >> 2, c4 = (t & 3) * 4;
      *(uint2*)&Vt[row * PS + 112 + c4] = make_uint2(0u, 0u);
    }
  }
  __syncthreads();

  // ---- phase 3: S = Q K^T. wave w owns m-tiles {w, w+4} (wave 3: {3}) ----
  const int nmt = (w < 3) ? 2 : 1;
  const int mt0 = w, mt1 = w + 4;

  f32x4 accs[2][7];
#pragma unroll
  for (int im = 0; im < 2; ++im) {
    if (im < nmt) {
      const int mt = (im == 0) ? mt0 : mt1;
      const int ar = (mt * 16 + cl) * QKS + q * 8;
      short8 a0 = *(const short8*)&Qs[ar];
      short8 a1 = *(const short8*)&Qs[ar + 32];
      __builtin_amdgcn_s_setprio(1);
#pragma unroll
      for (int nt = 0; nt < 7; ++nt) {
        const int br = (nt * 16 + cl) * QKS + q * 8;
        short8 b0 = *(const short8*)&Ks[br];
        short8 b1 = *(const short8*)&Ks[br + 32];
        f32x4 c = {};
        c = __builtin_amdgcn_mfma_f32_16x16x32_bf16(a0, b0, c, 0, 0, 0);
        c = __builtin_amdgcn_mfma_f32_16x16x32_bf16(a1, b1, c, 0, 0, 0);
        accs[im][nt] = c;
      }
      __builtin_amdgcn_s_setprio(0);
    }
  }

  // softmax over cols 0..99 (100..111 masked), in registers
  const float scale = 0.125f;  // 1/sqrt(64)
#pragma unroll
  for (int im = 0; im < 2; ++im) {
    if (im < nmt) {
#pragma unroll
      for (int r = 0; r < 4; ++r) {
        float mx = -1e30f;
#pragma unroll
        for (int nt = 0; nt < 7; ++nt) {
          float s = accs[im][nt][r] * scale;
          if ((nt < 6) || (cl < 4)) mx = fmaxf(mx, s);
        }
        mx = fmaxf(mx, __shfl_xor(mx, 1, 64));
        mx = fmaxf(mx, __shfl_xor(mx, 2, 64));
        mx = fmaxf(mx, __shfl_xor(mx, 4, 64));
        mx = fmaxf(mx, __shfl_xor(mx, 8, 64));
        float sum = 0.f;
#pragma unroll
        for (int nt = 0; nt < 7; ++nt) {
          float s = accs[im][nt][r] * scale;
          bool valid = (nt < 6) || (cl < 4);
          float e = valid ? __expf(s - mx) : 0.f;
          accs[im][nt][r] = e;
          sum += e;
        }
        sum += __shfl_xor(sum, 1, 64);
        sum += __shfl_xor(sum, 2, 64);
        sum += __shfl_xor(sum, 4, 64);
        sum += __shfl_xor(sum, 8, 64);
        float inv = 1.0f / sum;
#pragma unroll
        for (int nt = 0; nt < 7; ++nt) accs[im][nt][r] *= inv;
      }
    }
  }
  __syncthreads();  // Qs/Ks reads drained before P overwrites them

  // ---- phase 4: P write + PV ----
#pragma unroll
  for (int im = 0; im < 2; ++im) {
    if (im < nmt) {
      const int mt = (im == 0) ? mt0 : mt1;
#pragma unroll
      for (int nt = 0; nt < 7; ++nt)
#pragma unroll
        for (int r = 0; r < 4; ++r)
          P[(mt * 16 + q * 4 + r) * PS + nt * 16 + cl] = f2bf(accs[im][nt][r]);
    }
  }
  // zero P pad cols 112..127 (PV ks=3 reads up to col 127): 112 rows x 4 b64
#pragma unroll
  for (int k2 = 0; k2 < 2; ++k2) {
    const int s = k2 * 256 + t;
    if (s < 448) {
      const int row = s >> 2, c4 = (s & 3) * 4;
      *(uint2*)&P[row * PS + 112 + c4] = make_uint2(0u, 0u);
    }
  }
  __syncthreads();

  f32x4 acco[2][4] = {};
#pragma unroll
  for (int ks = 0; ks < 4; ++ks) {
    const int ko = ks * 32 + q * 8;
    short8 a0 = *(const short8*)&P[(mt0 * 16 + cl) * PS + ko];
    short8 a1 = a0;
    if (nmt == 2) a1 = *(const short8*)&P[(mt1 * 16 + cl) * PS + ko];
    __builtin_amdgcn_s_setprio(1);
#pragma unroll
    for (int nt = 0; nt < 4; ++nt) {
      short8 b = *(const short8*)&Vt[(nt * 16 + cl) * PS + ko];
      acco[0][nt] = __builtin_amdgcn_mfma_f32_16x16x32_bf16(a0, b, acco[0][nt], 0, 0, 0);
      if (nmt == 2)
        acco[1][nt] = __builtin_amdgcn_mfma_f32_16x16x32_bf16(a1, b, acco[1][nt], 0, 0, 0);
    }
    __builtin_amdgcn_s_setprio(0);
  }

  u16* obuf = (u16*)(ws + OFF_OBUF);
  const size_t orow0 = (size_t)win * WIN_SZ;
#pragma unroll
  for (int im = 0; im < 2; ++im) {
    if (im < nmt) {
      const int mt = (im == 0) ? mt0 : mt1;
#pragma unroll
      for (int nt = 0; nt < 4; ++nt)
#pragma unroll
        for (int r = 0; r < 4; ++r) {
          int row = mt * 16 + q * 4 + r;
          if (row < WIN_SZ)
            obuf[(orow0 + row) * DM + h * KD + nt * 16 + cl] = f2bf(acco[im][nt][r]);
        }
    }
  }
}

// ---------------- GEMM: C[M,N] = A[M,512] @ Bt[N,512]^T + bias (fp32 out) ----------------
__global__ __launch_bounds__(256, 4)
void gemm_k(const u16* __restrict__ ws, unsigned aoff0, unsigned btoff,
            unsigned biasoff, float* __restrict__ Cout, int Ntot) {
  __shared__ u16 Alds[128 * 64];
  __shared__ u16 Blds[128 * 64];

  const int t = threadIdx.x;
  const int w = t >> 6;
  const int l = t & 63;
  const int nb = blockIdx.x, mb = blockIdx.y;
  const int m0 = mb * 128, n0 = nb * 128;
  const int lr = t >> 3;
  // same G4/T2 swizzle as qkvattn_k phase 1 (128B row stride)
  const int lsw = (((t & 7) ^ ((t >> 3) & 7)) * 8);

  unsigned aoff[4], boff[4];
#pragma unroll
  for (int i = 0; i < 4; ++i) {
    int m = m0 + i * 32 + lr;
    aoff[i] = (m < MROWS) ? (aoff0 + (unsigned)m * DM + lsw) : OFF_ZBLK;
    boff[i] = btoff + (unsigned)(n0 + i * 32 + lr) * DM + lsw;
  }

  f32x4 acc[4][4] = {};
  const int wm = (w & 1) * 64;
  const int wn = (w >> 1) * 64;
  const int q = l >> 4, cl = l & 15;

  for (int k0 = 0; k0 < DM; k0 += 64) {
    __syncthreads();
#pragma unroll
    for (int i = 0; i < 4; ++i) {
      gl2lds16(ws + aoff[i] + (aoff[i] == OFF_ZBLK ? 0u : (unsigned)k0),
               &Alds[(i * 32 + w * 8) * 64]);
      gl2lds16(ws + boff[i] + k0, &Blds[(i * 32 + w * 8) * 64]);
    }
    __syncthreads();
#pragma unroll
    for (int ks = 0; ks < 2; ++ks) {
      short8 av[4], bv_[4];
      const int ko = ks * 32 + q * 8;
      const int koS = ko ^ ((cl & 7) << 3);   // read-side swizzle
#pragma unroll
      for (int mi = 0; mi < 4; ++mi)
        av[mi] = *(const short8*)&Alds[(wm + mi * 16 + cl) * 64 + koS];
#pragma unroll
      for (int ni = 0; ni < 4; ++ni)
        bv_[ni] = *(const short8*)&Blds[(wn + ni * 16 + cl) * 64 + koS];
      __builtin_amdgcn_s_setprio(1);
#pragma unroll
      for (int mi = 0; mi < 4; ++mi)
#pragma unroll
        for (int ni = 0; ni < 4; ++ni)
          acc[mi][ni] = __builtin_amdgcn_mfma_f32_16x16x32_bf16(
              av[mi], bv_[ni], acc[mi][ni], 0, 0, 0);
      __builtin_amdgcn_s_setprio(0);
    }
  }

  const float* biasF = (const float*)(ws + biasoff);
#pragma unroll
  for (int mi = 0; mi < 4; ++mi) {
#pragma unroll
    for (int ni = 0; ni < 4; ++ni) {
      int col = n0 + wn + ni * 16 + cl;
      float bb = biasF[col];
#pragma unroll
      for (int r = 0; r < 4; ++r) {
        int row = m0 + wm + mi * 16 + q * 4 + r;
        if (row < MROWS)
          Cout[(size_t)row * Ntot + col] = acc[mi][ni][r] + bb;
      }
    }
  }
}

extern "C" void kernel_launch(void* const* d_in, const int* in_sizes, int n_in,
                              void* d_out, int out_size, void* d_ws, size_t ws_size,
                              hipStream_t stream) {
  const float* x  = (const float*)d_in[0];
  const float* Wq = (const float*)d_in[1];
  const float* bq = (const float*)d_in[2];
  const float* Wk = (const float*)d_in[3];
  const float* bk = (const float*)d_in[4];
  const float* Wv = (const float*)d_in[5];
  const float* bv = (const float*)d_in[6];
  const float* Wo = (const float*)d_in[7];
  const float* bo = (const float*)d_in[8];

  u16* ws = (u16*)d_ws;

  prep_k<<<dim3(8, 8, 4), dim3(256), 0, stream>>>(
      Wq, Wk, Wv, Wo, bq, bk, bv, bo, ws);
  convx_k<<<dim3((MROWS * 128 + 255) / 256), dim3(256), 0, stream>>>(x, ws);
  qkvattn_k<<<dim3(NWINS, NHEAD), dim3(256), 0, stream>>>(ws);
  gemm_k<<<dim3(DM / 128, MBLKS), dim3(256), 0, stream>>>(
      ws, OFF_OBUF, OFF_WOT, OFF_BIAS2, (float*)d_out, DM);
}

// Round 8
// 247.453 us; speedup vs baseline: 1.3297x; 1.0061x over previous
//
#include <hip/hip_runtime.h>

typedef unsigned short u16;
typedef __attribute__((ext_vector_type(4))) float f32x4;
typedef __attribute__((ext_vector_type(8))) short short8;
typedef __attribute__((ext_vector_type(4))) short short4v;

#define WIN_SZ 100
#define NWIN 41
#define NBATCH 8
#define SEQ 4096
#define DM 512
#define NHEAD 8
#define KD 64
#define NWINS (NBATCH * NWIN)    // 328
#define MROWS (NWINS * WIN_SZ)   // 32800
#define MBLKS 257                // ceil(32800/128)
#define TOKPB (NWIN * WIN_SZ)    // 4100
#define NQKV 1536
#define CONV_BLKS ((MROWS * 128 + 255) / 256)   // 16400

// ws layout (u16 element offsets)
#define OFF_XBF   0u
#define OFF_OBUF  16793600u                 // + MROWS*DM
#define OFF_WQKVT 33587200u                 // + MROWS*DM
#define OFF_WOT   34373632u                 // + NQKV*DM
#define OFF_ZBLK  34635776u                 // + DM*DM
#define OFF_BIAS  34636032u                 // + 256   (1536 fp32 qkv bias)
#define OFF_BIAS2 34639104u                 // + 3072  (512 fp32 bo)

// 16x16x16 bf16 MFMA (K=16): B-frag k-slice (l>>4)*4+e matches the in-register
// P layout after swapped-QK^T, so PV needs no cross-lane P redistribution.
// NOTE: no __has_builtin guard — it returns false in the HOST pass of hipcc
// (aux-target builtins are callable there but not listed), which broke r6/r7.
// __builtin_amdgcn_mfma_f32_16x16x16bf16_1k: V4f(V4s,V4s,V4f,i,i,i), mai-insts,
// maps to v_mfma_f32_16x16x16_bf16 (valid gfx950, cdna4_isa.md §10).
#define MFMA16(a, b, c) __builtin_amdgcn_mfma_f32_16x16x16bf16_1k(a, b, c, 0, 0, 0)

__device__ __forceinline__ u16 f2bf(float f) {
  union { float f; unsigned i; } v; v.f = f;
  unsigned r = (v.i + 0x7fffu + ((v.i >> 16) & 1u)) >> 16;
  return (u16)r;
}

// async global->LDS, 16B per lane; lds base wave-uniform (HW adds lane*16)
__device__ __forceinline__ void gl2lds16(const void* g, void* lds) {
  __builtin_amdgcn_global_load_lds(
      (const __attribute__((address_space(1))) void*)g,
      (__attribute__((address_space(3))) void*)lds, 16, 0, 0);
}

// ---------- merged: x fp32->bf16 window gather (blocks [0,CONV_BLKS)) ----------
// ---------- + weight transposes / biases / zblk (blocks [CONV_BLKS, +256)) ----
__global__ void prepx_k(const float* __restrict__ x,
                        const float* __restrict__ Wq, const float* __restrict__ Wk,
                        const float* __restrict__ Wv, const float* __restrict__ Wo,
                        const float* __restrict__ bq, const float* __restrict__ bk,
                        const float* __restrict__ bv, const float* __restrict__ bo,
                        u16* __restrict__ ws) {
  __shared__ u16 tile[64][65];
  const int t = threadIdx.x;
  if (blockIdx.x < CONV_BLKS) {
    // ---- convx half ----
    u16* xbf = ws + OFF_XBF;
    int i = blockIdx.x * 256 + t;               // float4-group index
    if (i >= MROWS * 128) return;
    int m = i >> 7;
    int c4 = (i & 127) * 4;
    int b = m / TOKPB, tk = m - b * TOKPB;
    float4 v = make_float4(0.f, 0.f, 0.f, 0.f);
    if (tk < SEQ) v = *(const float4*)(x + (size_t)(b * SEQ + tk) * DM + c4);
    u16 o[4] = {f2bf(v.x), f2bf(v.y), f2bf(v.z), f2bf(v.w)};
    *(uint2*)(xbf + (size_t)m * DM + c4) = *(const uint2*)o;
    return;
  }
  // ---- prep half: p -> (bx, by, z) of the old dim3(8,8,4) grid ----
  const int p = blockIdx.x - CONV_BLKS;
  const int z = p >> 6, by = (p >> 3) & 7, bx = p & 7;
  const float* src = (z == 0) ? Wq : (z == 1) ? Wk : (z == 2) ? Wv : Wo;
  u16* dst = (z < 3) ? (ws + OFF_WQKVT + (unsigned)z * 512u * 512u)
                     : (ws + OFF_WOT);
  const int k0 = by * 64, n0 = bx * 64;
  const int c = t & 63, r4 = t >> 6;
#pragma unroll
  for (int pp = 0; pp < 16; ++pp) {
    int r = pp * 4 + r4;
    tile[r][c] = f2bf(src[(size_t)(k0 + r) * 512 + n0 + c]);
  }
  __syncthreads();
#pragma unroll
  for (int pp = 0; pp < 16; ++pp) {
    int r = pp * 4 + r4;                       // n index within tile
    dst[(size_t)(n0 + r) * 512 + k0 + c] = tile[c][r];
  }
  if (bx == 0 && by == 0) {
    float* biasF = (float*)(ws + OFF_BIAS);
    float* biasO = (float*)(ws + OFF_BIAS2);
    for (int j = t; j < 512; j += 256) {
      if (z == 0) biasF[j] = bq[j];
      else if (z == 1) biasF[512 + j] = bk[j];
      else if (z == 2) biasF[1024 + j] = bv[j];
      else biasO[j] = bo[j];
    }
    if (z == 3 && t < 128) ws[OFF_ZBLK + t] = 0;
  }
}

// -------------- fused QKV projection + attention, one block per (win, head) --------------
#define QKS 72   // Qs/Ks stride
#define PS 136   // Vt stride
// LDS phase-union (u16 elems), total 24832 (49664 B -> 3 blocks/CU):
//   phase1 (staging, dies at post-loop barrier): Xs [0,7168) + Wsl [7168,19456)
//   phase2+: Vt [0,8704) | Qs [8704,16768) | Ks [16768,24832)
//   (no P buffer: softmax->PV stays in registers via swapped QK^T + K=16 PV)
#define SM_ELEMS 24832

__global__ __launch_bounds__(256, 3)
void qkvattn_k(const u16* __restrict__ ws) {
  __shared__ u16 smem[SM_ELEMS];
  u16* Xs  = smem;              // 112 x 64 (column-slot XOR-swizzled per row)
  u16* Wsl = smem + 7168;       // 192 x 64 (column-slot XOR-swizzled per row)
  u16* Vt  = smem;              // 64 x 136
  u16* Qs  = smem + 8704;       // 112 x 72
  u16* Ks  = smem + 16768;      // 112 x 72

  const int win = blockIdx.x, h = blockIdx.y;
  const int t = threadIdx.x, w = t >> 6, l = t & 63;
  const int q = l >> 4, cl = l & 15;
  // Bank-conflict fix (G4/T2, m173 pattern): pre-swizzle the GLOBAL source
  // column; read-side XOR undoes it. 128B row stride otherwise 16-way conflicts.
  const int lsw = (((t & 7) ^ ((t >> 3) & 7)) * 8);

  // staging source offsets (column pre-swizzled)
  unsigned xoff[4];
#pragma unroll
  for (int i = 0; i < 4; ++i) {
    int m = i * 32 + (t >> 3);
    xoff[i] = (m < WIN_SZ)
                  ? (OFF_XBF + (unsigned)(win * WIN_SZ + m) * DM + lsw)
                  : OFF_ZBLK;
  }
  unsigned woff[6];
#pragma unroll
  for (int i = 0; i < 6; ++i) {
    int g = i * 32 + (t >> 3);
    unsigned nrow = (unsigned)(g >> 6) * 512u + (unsigned)h * 64u + (g & 63);
    woff[i] = OFF_WQKVT + nrow * DM + lsw;
  }

  // ---- phase 1: QKV projection. wave w owns n-tiles {3w,3w+1,3w+2} of 12 ----
  f32x4 acc_p[7][3] = {};
  for (int k0 = 0; k0 < DM; k0 += 64) {
    __syncthreads();
#pragma unroll
    for (int i = 0; i < 4; ++i)
      if (i * 32 + w * 8 < 112)   // wave-uniform
        gl2lds16(ws + xoff[i] + (xoff[i] == OFF_ZBLK ? 0u : (unsigned)k0),
                 &Xs[(i * 32 + w * 8) * 64]);
#pragma unroll
    for (int i = 0; i < 6; ++i)
      gl2lds16(ws + woff[i] + k0, &Wsl[(i * 32 + w * 8) * 64]);
    __syncthreads();
#pragma unroll
    for (int ks = 0; ks < 2; ++ks) {
      const int ko = ks * 32 + q * 8;
      const int koS = ko ^ ((cl & 7) << 3);   // read-side swizzle
      short8 af[7], bf[3];
#pragma unroll
      for (int mt = 0; mt < 7; ++mt)
        af[mt] = *(const short8*)&Xs[(mt * 16 + cl) * 64 + koS];
#pragma unroll
      for (int ntl = 0; ntl < 3; ++ntl)
        bf[ntl] = *(const short8*)&Wsl[((3 * w + ntl) * 16 + cl) * 64 + koS];
      __builtin_amdgcn_s_setprio(1);
#pragma unroll
      for (int mt = 0; mt < 7; ++mt)
#pragma unroll
        for (int ntl = 0; ntl < 3; ++ntl)
          acc_p[mt][ntl] = __builtin_amdgcn_mfma_f32_16x16x32_bf16(
              af[mt], bf[ntl], acc_p[mt][ntl], 0, 0, 0);
      __builtin_amdgcn_s_setprio(0);
    }
  }
  __syncthreads();  // staging reads drained; Vt/Qs/Ks may now overwrite

  // ---- phase 2: accs (+bias) -> Qs / Ks / Vt ----
  {
    const float* biasF = (const float*)(ws + OFF_BIAS);
#pragma unroll
    for (int ntl = 0; ntl < 3; ++ntl) {
      const int nt = 3 * w + ntl;                      // wave-uniform
      const int cw = (nt & 3) * 16 + cl;               // col within Q/K/V
      const float bb = biasF[(nt >> 2) * 512 + h * 64 + cw];
      if (nt < 8) {
        u16* dst = (nt < 4) ? Qs : Ks;
#pragma unroll
        for (int mt = 0; mt < 7; ++mt)
#pragma unroll
          for (int r = 0; r < 4; ++r) {
            const int tok = mt * 16 + q * 4 + r;
            dst[tok * QKS + cw] = f2bf(acc_p[mt][ntl][r] + bb);
          }
      } else {
        // V: r-index is contiguous in Vt -> pack 4 u16 into one b64 write
#pragma unroll
        for (int mt = 0; mt < 7; ++mt) {
          u16 pkv[4];
#pragma unroll
          for (int r = 0; r < 4; ++r) pkv[r] = f2bf(acc_p[mt][ntl][r] + bb);
          *(uint2*)&Vt[cw * PS + mt * 16 + q * 4] = *(const uint2*)pkv;
        }
      }
    }
    // no Vt pad zeroing needed: PV only reads tokens 0..111 (K=16 tiles),
    // and tokens 100..111 are killed by P=0 from the softmax mask.
  }
  __syncthreads();

  // ---- phase 3: S^T = K Q^T (swapped operands). wave w owns Q-tiles {w, w+4} ----
  // D layout: row = token = nt*16 + q*4 + r (A=K side), col = Q-row = mt*16 + cl.
  const int nmt = (w < 3) ? 2 : 1;
  const int mt0 = w, mt1 = w + 4;

  f32x4 accs[2][7];
#pragma unroll
  for (int im = 0; im < 2; ++im) {
    if (im < nmt) {
      const int mt = (im == 0) ? mt0 : mt1;
      const int ar = (mt * 16 + cl) * QKS + q * 8;
      short8 qa0 = *(const short8*)&Qs[ar];
      short8 qa1 = *(const short8*)&Qs[ar + 32];
      __builtin_amdgcn_s_setprio(1);
#pragma unroll
      for (int nt = 0; nt < 7; ++nt) {
        const int br = (nt * 16 + cl) * QKS + q * 8;
        short8 kb0 = *(const short8*)&Ks[br];
        short8 kb1 = *(const short8*)&Ks[br + 32];
        f32x4 c = {};
        c = __builtin_amdgcn_mfma_f32_16x16x32_bf16(kb0, qa0, c, 0, 0, 0);
        c = __builtin_amdgcn_mfma_f32_16x16x32_bf16(kb1, qa1, c, 0, 0, 0);
        accs[im][nt] = c;
      }
      __builtin_amdgcn_s_setprio(0);
    }
  }

  // softmax over tokens (in-lane 28 values + 2 shfl over the q-group),
  // then pack P to bf16 pairs in-register: pk[im][nt][j] holds tokens
  // nt*16 + 4q + {2j, 2j+1} -- exactly the 16x16x16 B-frag k-slice.
  const float scale = 0.125f;  // 1/sqrt(64)
  unsigned pk[2][7][2];
#pragma unroll
  for (int im = 0; im < 2; ++im) {
    if (im < nmt) {
      float mx = -1e30f;
#pragma unroll
      for (int nt = 0; nt < 7; ++nt)
#pragma unroll
        for (int r = 0; r < 4; ++r) {
          float s = accs[im][nt][r] * scale;
          accs[im][nt][r] = s;
          if ((nt < 6) || (q == 0)) mx = fmaxf(mx, s);   // token<100 valid
        }
      mx = fmaxf(mx, __shfl_xor(mx, 16, 64));
      mx = fmaxf(mx, __shfl_xor(mx, 32, 64));
      float sum = 0.f;
#pragma unroll
      for (int nt = 0; nt < 7; ++nt)
#pragma unroll
        for (int r = 0; r < 4; ++r) {
          bool valid = (nt < 6) || (q == 0);
          float e = valid ? __expf(accs[im][nt][r] - mx) : 0.f;
          accs[im][nt][r] = e;
          sum += e;
        }
      sum += __shfl_xor(sum, 16, 64);
      sum += __shfl_xor(sum, 32, 64);
      float inv = 1.0f / sum;
#pragma unroll
      for (int nt = 0; nt < 7; ++nt) {
        pk[im][nt][0] = (unsigned)f2bf(accs[im][nt][0] * inv) |
                        ((unsigned)f2bf(accs[im][nt][1] * inv) << 16);
        pk[im][nt][1] = (unsigned)f2bf(accs[im][nt][2] * inv) |
                        ((unsigned)f2bf(accs[im][nt][3] * inv) << 16);
      }
    }
  }
  // no barrier needed: PV reads only Vt (written before the phase-2 barrier)

  // ---- phase 4: O^T = V^T P^T via K=16 MFMA, P straight from registers ----
  // D: col = Q-row = mt*16+cl, row = kd = vt*16 + q*4 + r.
  f32x4 acco[2][4] = {};
  __builtin_amdgcn_s_setprio(1);
#pragma unroll
  for (int vt = 0; vt < 4; ++vt) {
#pragma unroll
    for (int nt = 0; nt < 7; ++nt) {
      short4v av = *(const short4v*)&Vt[(vt * 16 + cl) * PS + nt * 16 + q * 4];
      union { unsigned u[2]; short4v s; } b0, b1;
      b0.u[0] = pk[0][nt][0]; b0.u[1] = pk[0][nt][1];
      acco[0][vt] = MFMA16(av, b0.s, acco[0][vt]);
      if (nmt == 2) {
        b1.u[0] = pk[1][nt][0]; b1.u[1] = pk[1][nt][1];
        acco[1][vt] = MFMA16(av, b1.s, acco[1][vt]);
      }
    }
  }
  __builtin_amdgcn_s_setprio(0);

  // ---- epilogue: packed 8B stores, kd contiguous per lane ----
  u16* obuf = (u16*)(ws + OFF_OBUF);
  const size_t orow0 = (size_t)win * WIN_SZ;
#pragma unroll
  for (int im = 0; im < 2; ++im) {
    if (im < nmt) {
      const int mt = (im == 0) ? mt0 : mt1;
      const int row = mt * 16 + cl;
      if (row < WIN_SZ) {
#pragma unroll
        for (int vt = 0; vt < 4; ++vt) {
          u16 ov[4];
#pragma unroll
          for (int r = 0; r < 4; ++r) ov[r] = f2bf(acco[im][vt][r]);
          *(uint2*)&obuf[(orow0 + row) * DM + h * KD + vt * 16 + q * 4] =
              *(const uint2*)ov;
        }
      }
    }
  }
}

// ---------------- GEMM: C[M,N] = A[M,512] @ Bt[N,512]^T + bias (fp32 out) ----------------
__global__ __launch_bounds__(256, 4)
void gemm_k(const u16* __restrict__ ws, unsigned aoff0, unsigned btoff,
            unsigned biasoff, float* __restrict__ Cout, int Ntot) {
  __shared__ u16 Alds[128 * 64];
  __shared__ u16 Blds[128 * 64];

  const int t = threadIdx.x;
  const int w = t >> 6;
  const int l = t & 63;
  const int nb = blockIdx.x, mb = blockIdx.y;
  const int m0 = mb * 128, n0 = nb * 128;
  const int lr = t >> 3;
  // same G4/T2 swizzle as qkvattn_k phase 1 (128B row stride)
  const int lsw = (((t & 7) ^ ((t >> 3) & 7)) * 8);

  unsigned aoff[4], boff[4];
#pragma unroll
  for (int i = 0; i < 4; ++i) {
    int m = m0 + i * 32 + lr;
    aoff[i] = (m < MROWS) ? (aoff0 + (unsigned)m * DM + lsw) : OFF_ZBLK;
    boff[i] = btoff + (unsigned)(n0 + i * 32 + lr) * DM + lsw;
  }

  f32x4 acc[4][4] = {};
  const int wm = (w & 1) * 64;
  const int wn = (w >> 1) * 64;
  const int q = l >> 4, cl = l & 15;

  for (int k0 = 0; k0 < DM; k0 += 64) {
    __syncthreads();
#pragma unroll
    for (int i = 0; i < 4; ++i) {
      gl2lds16(ws + aoff[i] + (aoff[i] == OFF_ZBLK ? 0u : (unsigned)k0),
               &Alds[(i * 32 + w * 8) * 64]);
      gl2lds16(ws + boff[i] + k0, &Blds[(i * 32 + w * 8) * 64]);
    }
    __syncthreads();
#pragma unroll
    for (int ks = 0; ks < 2; ++ks) {
      short8 av[4], bv_[4];
      const int ko = ks * 32 + q * 8;
      const int koS = ko ^ ((cl & 7) << 3);   // read-side swizzle
#pragma unroll
      for (int mi = 0; mi < 4; ++mi)
        av[mi] = *(const short8*)&Alds[(wm + mi * 16 + cl) * 64 + koS];
#pragma unroll
      for (int ni = 0; ni < 4; ++ni)
        bv_[ni] = *(const short8*)&Blds[(wn + ni * 16 + cl) * 64 + koS];
      __builtin_amdgcn_s_setprio(1);
#pragma unroll
      for (int mi = 0; mi < 4; ++mi)
#pragma unroll
        for (int ni = 0; ni < 4; ++ni)
          acc[mi][ni] = __builtin_amdgcn_mfma_f32_16x16x32_bf16(
              av[mi], bv_[ni], acc[mi][ni], 0, 0, 0);
      __builtin_amdgcn_s_setprio(0);
    }
  }

  const float* biasF = (const float*)(ws + biasoff);
#pragma unroll
  for (int mi = 0; mi < 4; ++mi) {
#pragma unroll
    for (int ni = 0; ni < 4; ++ni) {
      int col = n0 + wn + ni * 16 + cl;
      float bb = biasF[col];
#pragma unroll
      for (int r = 0; r < 4; ++r) {
        int row = m0 + wm + mi * 16 + q * 4 + r;
        if (row < MROWS)
          Cout[(size_t)row * Ntot + col] = acc[mi][ni][r] + bb;
      }
    }
  }
}

extern "C" void kernel_launch(void* const* d_in, const int* in_sizes, int n_in,
                              void* d_out, int out_size, void* d_ws, size_t ws_size,
                              hipStream_t stream) {
  const float* x  = (const float*)d_in[0];
  const float* Wq = (const float*)d_in[1];
  const float* bq = (const float*)d_in[2];
  const float* Wk = (const float*)d_in[3];
  const float* bk = (const float*)d_in[4];
  const float* Wv = (const float*)d_in[5];
  const float* bv = (const float*)d_in[6];
  const float* Wo = (const float*)d_in[7];
  const float* bo = (const float*)d_in[8];

  u16* ws = (u16*)d_ws;

  prepx_k<<<dim3(CONV_BLKS + 256), dim3(256), 0, stream>>>(
      x, Wq, Wk, Wv, Wo, bq, bk, bv, bo, ws);
  qkvattn_k<<<dim3(NWINS, NHEAD), dim3(256), 0, stream>>>(ws);
  gemm_k<<<dim3(DM / 128, MBLKS), dim3(256), 0, stream>>>(
      ws, OFF_OBUF, OFF_WOT, OFF_BIAS2, (float*)d_out, DM);
}

// Round 9
// 246.015 us; speedup vs baseline: 1.3374x; 1.0058x over previous
//
#include <hip/hip_runtime.h>

typedef unsigned short u16;
typedef __attribute__((ext_vector_type(4))) float f32x4;
typedef __attribute__((ext_vector_type(8))) short short8;
typedef __attribute__((ext_vector_type(4))) short short4v;

#define WIN_SZ 100
#define NWIN 41
#define NBATCH 8
#define SEQ 4096
#define DM 512
#define NHEAD 8
#define KD 64
#define NWINS (NBATCH * NWIN)    // 328
#define MROWS (NWINS * WIN_SZ)   // 32800
#define MBLKS 257                // ceil(32800/128)
#define TOKPB (NWIN * WIN_SZ)    // 4100
#define NQKV 1536
#define CONV_BLKS ((MROWS * 128 + 255) / 256)   // 16400
#define GEMM_BLKS (((MBLKS + 7) / 8) * 32)      // 33 panel-groups * 32 = 1056

// ws layout (u16 element offsets)
#define OFF_XBF   0u
#define OFF_OBUF  16793600u                 // + MROWS*DM
#define OFF_WQKVT 33587200u                 // + MROWS*DM
#define OFF_WOT   34373632u                 // + NQKV*DM
#define OFF_ZBLK  34635776u                 // + DM*DM
#define OFF_BIAS  34636032u                 // + 256   (1536 fp32 qkv bias)
#define OFF_BIAS2 34639104u                 // + 3072  (512 fp32 bo)

// 16x16x16 bf16 MFMA (K=16): B-frag k-slice (l>>4)*4+e matches the in-register
// P layout after swapped-QK^T, so PV needs no cross-lane P redistribution.
// NOTE: no __has_builtin guard — it returns false in the HOST pass of hipcc
// (aux-target builtins are callable there but not listed), which broke r6/r7.
#define MFMA16(a, b, c) __builtin_amdgcn_mfma_f32_16x16x16bf16_1k(a, b, c, 0, 0, 0)

__device__ __forceinline__ u16 f2bf(float f) {
  union { float f; unsigned i; } v; v.f = f;
  unsigned r = (v.i + 0x7fffu + ((v.i >> 16) & 1u)) >> 16;
  return (u16)r;
}

// async global->LDS, 16B per lane; lds base wave-uniform (HW adds lane*16)
__device__ __forceinline__ void gl2lds16(const void* g, void* lds) {
  __builtin_amdgcn_global_load_lds(
      (const __attribute__((address_space(1))) void*)g,
      (__attribute__((address_space(3))) void*)lds, 16, 0, 0);
}

// ---------- merged: x fp32->bf16 window gather (blocks [0,CONV_BLKS)) ----------
// ---------- + weight transposes / biases / zblk (blocks [CONV_BLKS, +256)) ----
__global__ void prepx_k(const float* __restrict__ x,
                        const float* __restrict__ Wq, const float* __restrict__ Wk,
                        const float* __restrict__ Wv, const float* __restrict__ Wo,
                        const float* __restrict__ bq, const float* __restrict__ bk,
                        const float* __restrict__ bv, const float* __restrict__ bo,
                        u16* __restrict__ ws) {
  __shared__ u16 tile[64][65];
  const int t = threadIdx.x;
  if (blockIdx.x < CONV_BLKS) {
    // ---- convx half ----
    u16* xbf = ws + OFF_XBF;
    int i = blockIdx.x * 256 + t;               // float4-group index
    if (i >= MROWS * 128) return;
    int m = i >> 7;
    int c4 = (i & 127) * 4;
    int b = m / TOKPB, tk = m - b * TOKPB;
    float4 v = make_float4(0.f, 0.f, 0.f, 0.f);
    if (tk < SEQ) v = *(const float4*)(x + (size_t)(b * SEQ + tk) * DM + c4);
    u16 o[4] = {f2bf(v.x), f2bf(v.y), f2bf(v.z), f2bf(v.w)};
    *(uint2*)(xbf + (size_t)m * DM + c4) = *(const uint2*)o;
    return;
  }
  // ---- prep half: p -> (bx, by, z) of the old dim3(8,8,4) grid ----
  const int p = blockIdx.x - CONV_BLKS;
  const int z = p >> 6, by = (p >> 3) & 7, bx = p & 7;
  const float* src = (z == 0) ? Wq : (z == 1) ? Wk : (z == 2) ? Wv : Wo;
  u16* dst = (z < 3) ? (ws + OFF_WQKVT + (unsigned)z * 512u * 512u)
                     : (ws + OFF_WOT);
  const int k0 = by * 64, n0 = bx * 64;
  const int c = t & 63, r4 = t >> 6;
#pragma unroll
  for (int pp = 0; pp < 16; ++pp) {
    int r = pp * 4 + r4;
    tile[r][c] = f2bf(src[(size_t)(k0 + r) * 512 + n0 + c]);
  }
  __syncthreads();
#pragma unroll
  for (int pp = 0; pp < 16; ++pp) {
    int r = pp * 4 + r4;                       // n index within tile
    dst[(size_t)(n0 + r) * 512 + k0 + c] = tile[c][r];
  }
  if (bx == 0 && by == 0) {
    float* biasF = (float*)(ws + OFF_BIAS);
    float* biasO = (float*)(ws + OFF_BIAS2);
    for (int j = t; j < 512; j += 256) {
      if (z == 0) biasF[j] = bq[j];
      else if (z == 1) biasF[512 + j] = bk[j];
      else if (z == 2) biasF[1024 + j] = bv[j];
      else biasO[j] = bo[j];
    }
    if (z == 3 && t < 128) ws[OFF_ZBLK + t] = 0;
  }
}

// -------------- fused QKV projection + attention, one block per (win, head) --------------
#define QKS 72   // Qs/Ks stride
#define PS 136   // Vt stride
// LDS phase-union (u16 elems), total 24832 (49664 B -> 3 blocks/CU):
//   phase1 (staging, dies at post-loop barrier): Xs [0,7168) + Wsl [7168,19456)
//   phase2+: Vt [0,8704) | Qs [8704,16768) | Ks [16768,24832)
//   (no P buffer: softmax->PV stays in registers via swapped QK^T + K=16 PV)
#define SM_ELEMS 24832

__global__ __launch_bounds__(256, 3)
void qkvattn_k(const u16* __restrict__ ws) {
  __shared__ u16 smem[SM_ELEMS];
  u16* Xs  = smem;              // 112 x 64 (column-slot XOR-swizzled per row)
  u16* Wsl = smem + 7168;       // 192 x 64 (column-slot XOR-swizzled per row)
  u16* Vt  = smem;              // 64 x 136
  u16* Qs  = smem + 8704;       // 112 x 72
  u16* Ks  = smem + 16768;      // 112 x 72

  // XCD-locality mapping (T1): all 8 heads of a window share f mod 8 (same
  // XCD L2, since their ids differ by multiples of 8) AND are consecutive in
  // that XCD's dispatch stream -> the 115KB X tile is staged 8x while L2-hot.
  // f = (win>>3)*64 + h*8 + (win&7); bijective over 328*8 = 2624.
  const int f = blockIdx.x;
  const int h = (f >> 3) & 7;
  const int win = ((f >> 6) << 3) + (f & 7);

  const int t = threadIdx.x, w = t >> 6, l = t & 63;
  const int q = l >> 4, cl = l & 15;
  // Bank-conflict fix (G4/T2, m173 pattern): pre-swizzle the GLOBAL source
  // column; read-side XOR undoes it. 128B row stride otherwise 16-way conflicts.
  const int lsw = (((t & 7) ^ ((t >> 3) & 7)) * 8);

  // staging source offsets (column pre-swizzled)
  unsigned xoff[4];
#pragma unroll
  for (int i = 0; i < 4; ++i) {
    int m = i * 32 + (t >> 3);
    xoff[i] = (m < WIN_SZ)
                  ? (OFF_XBF + (unsigned)(win * WIN_SZ + m) * DM + lsw)
                  : OFF_ZBLK;
  }
  unsigned woff[6];
#pragma unroll
  for (int i = 0; i < 6; ++i) {
    int g = i * 32 + (t >> 3);
    unsigned nrow = (unsigned)(g >> 6) * 512u + (unsigned)h * 64u + (g & 63);
    woff[i] = OFF_WQKVT + nrow * DM + lsw;
  }

  // ---- phase 1: QKV projection. wave w owns n-tiles {3w,3w+1,3w+2} of 12 ----
  f32x4 acc_p[7][3] = {};
  for (int k0 = 0; k0 < DM; k0 += 64) {
    __syncthreads();
#pragma unroll
    for (int i = 0; i < 4; ++i)
      if (i * 32 + w * 8 < 112)   // wave-uniform
        gl2lds16(ws + xoff[i] + (xoff[i] == OFF_ZBLK ? 0u : (unsigned)k0),
                 &Xs[(i * 32 + w * 8) * 64]);
#pragma unroll
    for (int i = 0; i < 6; ++i)
      gl2lds16(ws + woff[i] + k0, &Wsl[(i * 32 + w * 8) * 64]);
    __syncthreads();
#pragma unroll
    for (int ks = 0; ks < 2; ++ks) {
      const int ko = ks * 32 + q * 8;
      const int koS = ko ^ ((cl & 7) << 3);   // read-side swizzle
      short8 af[7], bf[3];
#pragma unroll
      for (int mt = 0; mt < 7; ++mt)
        af[mt] = *(const short8*)&Xs[(mt * 16 + cl) * 64 + koS];
#pragma unroll
      for (int ntl = 0; ntl < 3; ++ntl)
        bf[ntl] = *(const short8*)&Wsl[((3 * w + ntl) * 16 + cl) * 64 + koS];
      __builtin_amdgcn_s_setprio(1);
#pragma unroll
      for (int mt = 0; mt < 7; ++mt)
#pragma unroll
        for (int ntl = 0; ntl < 3; ++ntl)
          acc_p[mt][ntl] = __builtin_amdgcn_mfma_f32_16x16x32_bf16(
              af[mt], bf[ntl], acc_p[mt][ntl], 0, 0, 0);
      __builtin_amdgcn_s_setprio(0);
    }
  }
  __syncthreads();  // staging reads drained; Vt/Qs/Ks may now overwrite

  // ---- phase 2: accs (+bias) -> Qs / Ks / Vt ----
  {
    const float* biasF = (const float*)(ws + OFF_BIAS);
#pragma unroll
    for (int ntl = 0; ntl < 3; ++ntl) {
      const int nt = 3 * w + ntl;                      // wave-uniform
      const int cw = (nt & 3) * 16 + cl;               // col within Q/K/V
      const float bb = biasF[(nt >> 2) * 512 + h * 64 + cw];
      if (nt < 8) {
        u16* dst = (nt < 4) ? Qs : Ks;
#pragma unroll
        for (int mt = 0; mt < 7; ++mt)
#pragma unroll
          for (int r = 0; r < 4; ++r) {
            const int tok = mt * 16 + q * 4 + r;
            dst[tok * QKS + cw] = f2bf(acc_p[mt][ntl][r] + bb);
          }
      } else {
        // V: r-index is contiguous in Vt -> pack 4 u16 into one b64 write
#pragma unroll
        for (int mt = 0; mt < 7; ++mt) {
          u16 pkv[4];
#pragma unroll
          for (int r = 0; r < 4; ++r) pkv[r] = f2bf(acc_p[mt][ntl][r] + bb);
          *(uint2*)&Vt[cw * PS + mt * 16 + q * 4] = *(const uint2*)pkv;
        }
      }
    }
    // no Vt pad zeroing needed: PV only reads tokens 0..111 (K=16 tiles),
    // and tokens 100..111 are killed by P=0 from the softmax mask.
  }
  __syncthreads();

  // ---- phase 3: S^T = K Q^T (swapped operands). wave w owns Q-tiles {w, w+4} ----
  // D layout: row = token = nt*16 + q*4 + r (A=K side), col = Q-row = mt*16 + cl.
  const int nmt = (w < 3) ? 2 : 1;
  const int mt0 = w, mt1 = w + 4;

  f32x4 accs[2][7];
#pragma unroll
  for (int im = 0; im < 2; ++im) {
    if (im < nmt) {
      const int mt = (im == 0) ? mt0 : mt1;
      const int ar = (mt * 16 + cl) * QKS + q * 8;
      short8 qa0 = *(const short8*)&Qs[ar];
      short8 qa1 = *(const short8*)&Qs[ar + 32];
      __builtin_amdgcn_s_setprio(1);
#pragma unroll
      for (int nt = 0; nt < 7; ++nt) {
        const int br = (nt * 16 + cl) * QKS + q * 8;
        short8 kb0 = *(const short8*)&Ks[br];
        short8 kb1 = *(const short8*)&Ks[br + 32];
        f32x4 c = {};
        c = __builtin_amdgcn_mfma_f32_16x16x32_bf16(kb0, qa0, c, 0, 0, 0);
        c = __builtin_amdgcn_mfma_f32_16x16x32_bf16(kb1, qa1, c, 0, 0, 0);
        accs[im][nt] = c;
      }
      __builtin_amdgcn_s_setprio(0);
    }
  }

  // softmax over tokens (in-lane 28 values + 2 shfl over the q-group),
  // then pack P to bf16 pairs in-register: pk[im][nt][j] holds tokens
  // nt*16 + 4q + {2j, 2j+1} -- exactly the 16x16x16 B-frag k-slice.
  const float scale = 0.125f;  // 1/sqrt(64)
  unsigned pk[2][7][2];
#pragma unroll
  for (int im = 0; im < 2; ++im) {
    if (im < nmt) {
      float mx = -1e30f;
#pragma unroll
      for (int nt = 0; nt < 7; ++nt)
#pragma unroll
        for (int r = 0; r < 4; ++r) {
          float s = accs[im][nt][r] * scale;
          accs[im][nt][r] = s;
          if ((nt < 6) || (q == 0)) mx = fmaxf(mx, s);   // token<100 valid
        }
      mx = fmaxf(mx, __shfl_xor(mx, 16, 64));
      mx = fmaxf(mx, __shfl_xor(mx, 32, 64));
      float sum = 0.f;
#pragma unroll
      for (int nt = 0; nt < 7; ++nt)
#pragma unroll
        for (int r = 0; r < 4; ++r) {
          bool valid = (nt < 6) || (q == 0);
          float e = valid ? __expf(accs[im][nt][r] - mx) : 0.f;
          accs[im][nt][r] = e;
          sum += e;
        }
      sum += __shfl_xor(sum, 16, 64);
      sum += __shfl_xor(sum, 32, 64);
      float inv = 1.0f / sum;
#pragma unroll
      for (int nt = 0; nt < 7; ++nt) {
        pk[im][nt][0] = (unsigned)f2bf(accs[im][nt][0] * inv) |
                        ((unsigned)f2bf(accs[im][nt][1] * inv) << 16);
        pk[im][nt][1] = (unsigned)f2bf(accs[im][nt][2] * inv) |
                        ((unsigned)f2bf(accs[im][nt][3] * inv) << 16);
      }
    }
  }
  // no barrier needed: PV reads only Vt (written before the phase-2 barrier)

  // ---- phase 4: O^T = V^T P^T via K=16 MFMA, P straight from registers ----
  // D: col = Q-row = mt*16+cl, row = kd = vt*16 + q*4 + r.
  f32x4 acco[2][4] = {};
  __builtin_amdgcn_s_setprio(1);
#pragma unroll
  for (int vt = 0; vt < 4; ++vt) {
#pragma unroll
    for (int nt = 0; nt < 7; ++nt) {
      short4v av = *(const short4v*)&Vt[(vt * 16 + cl) * PS + nt * 16 + q * 4];
      union { unsigned u[2]; short4v s; } b0, b1;
      b0.u[0] = pk[0][nt][0]; b0.u[1] = pk[0][nt][1];
      acco[0][vt] = MFMA16(av, b0.s, acco[0][vt]);
      if (nmt == 2) {
        b1.u[0] = pk[1][nt][0]; b1.u[1] = pk[1][nt][1];
        acco[1][vt] = MFMA16(av, b1.s, acco[1][vt]);
      }
    }
  }
  __builtin_amdgcn_s_setprio(0);

  // ---- epilogue: packed 8B stores, kd contiguous per lane ----
  u16* obuf = (u16*)(ws + OFF_OBUF);
  const size_t orow0 = (size_t)win * WIN_SZ;
#pragma unroll
  for (int im = 0; im < 2; ++im) {
    if (im < nmt) {
      const int mt = (im == 0) ? mt0 : mt1;
      const int row = mt * 16 + cl;
      if (row < WIN_SZ) {
#pragma unroll
        for (int vt = 0; vt < 4; ++vt) {
          u16 ov[4];
#pragma unroll
          for (int r = 0; r < 4; ++r) ov[r] = f2bf(acco[im][vt][r]);
          *(uint2*)&obuf[(orow0 + row) * DM + h * KD + vt * 16 + q * 4] =
              *(const uint2*)ov;
        }
      }
    }
  }
}

// ---------------- GEMM: C[M,N] = A[M,512] @ Bt[N,512]^T + bias (fp32 out) ----------------
__global__ __launch_bounds__(256, 4)
void gemm_k(const u16* __restrict__ ws, unsigned aoff0, unsigned btoff,
            unsigned biasoff, float* __restrict__ Cout, int Ntot) {
  __shared__ u16 Alds[128 * 64];
  __shared__ u16 Blds[128 * 64];

  // XCD-locality mapping (T1): the 4 n-blocks sharing an A-panel get ids
  // differing by multiples of 8 (same XCD) and consecutive in that XCD's
  // stream -> the 131KB A-panel is read from HBM once, L2-hit 3x.
  // f = (p>>3)*32 + nb*8 + (p&7); panels padded to 264 (28 dummy blocks).
  const int f = blockIdx.x;
  const int nb = (f >> 3) & 3;
  const int p = ((f >> 5) << 3) + (f & 7);
  if (p >= MBLKS) return;

  const int t = threadIdx.x;
  const int w = t >> 6;
  const int l = t & 63;
  const int m0 = p * 128, n0 = nb * 128;
  const int lr = t >> 3;
  // same G4/T2 swizzle as qkvattn_k phase 1 (128B row stride)
  const int lsw = (((t & 7) ^ ((t >> 3) & 7)) * 8);

  unsigned aoff[4], boff[4];
#pragma unroll
  for (int i = 0; i < 4; ++i) {
    int m = m0 + i * 32 + lr;
    aoff[i] = (m < MROWS) ? (aoff0 + (unsigned)m * DM + lsw) : OFF_ZBLK;
    boff[i] = btoff + (unsigned)(n0 + i * 32 + lr) * DM + lsw;
  }

  f32x4 acc[4][4] = {};
  const int wm = (w & 1) * 64;
  const int wn = (w >> 1) * 64;
  const int q = l >> 4, cl = l & 15;

  for (int k0 = 0; k0 < DM; k0 += 64) {
    __syncthreads();
#pragma unroll
    for (int i = 0; i < 4; ++i) {
      gl2lds16(ws + aoff[i] + (aoff[i] == OFF_ZBLK ? 0u : (unsigned)k0),
               &Alds[(i * 32 + w * 8) * 64]);
      gl2lds16(ws + boff[i] + k0, &Blds[(i * 32 + w * 8) * 64]);
    }
    __syncthreads();
#pragma unroll
    for (int ks = 0; ks < 2; ++ks) {
      short8 av[4], bv_[4];
      const int ko = ks * 32 + q * 8;
      const int koS = ko ^ ((cl & 7) << 3);   // read-side swizzle
#pragma unroll
      for (int mi = 0; mi < 4; ++mi)
        av[mi] = *(const short8*)&Alds[(wm + mi * 16 + cl) * 64 + koS];
#pragma unroll
      for (int ni = 0; ni < 4; ++ni)
        bv_[ni] = *(const short8*)&Blds[(wn + ni * 16 + cl) * 64 + koS];
      __builtin_amdgcn_s_setprio(1);
#pragma unroll
      for (int mi = 0; mi < 4; ++mi)
#pragma unroll
        for (int ni = 0; ni < 4; ++ni)
          acc[mi][ni] = __builtin_amdgcn_mfma_f32_16x16x32_bf16(
              av[mi], bv_[ni], acc[mi][ni], 0, 0, 0);
      __builtin_amdgcn_s_setprio(0);
    }
  }

  const float* biasF = (const float*)(ws + biasoff);
#pragma unroll
  for (int mi = 0; mi < 4; ++mi) {
#pragma unroll
    for (int ni = 0; ni < 4; ++ni) {
      int col = n0 + wn + ni * 16 + cl;
      float bb = biasF[col];
#pragma unroll
      for (int r = 0; r < 4; ++r) {
        int row = m0 + wm + mi * 16 + q * 4 + r;
        if (row < MROWS)
          Cout[(size_t)row * Ntot + col] = acc[mi][ni][r] + bb;
      }
    }
  }
}

extern "C" void kernel_launch(void* const* d_in, const int* in_sizes, int n_in,
                              void* d_out, int out_size, void* d_ws, size_t ws_size,
                              hipStream_t stream) {
  const float* x  = (const float*)d_in[0];
  const float* Wq = (const float*)d_in[1];
  const float* bq = (const float*)d_in[2];
  const float* Wk = (const float*)d_in[3];
  const float* bk = (const float*)d_in[4];
  const float* Wv = (const float*)d_in[5];
  const float* bv = (const float*)d_in[6];
  const float* Wo = (const float*)d_in[7];
  const float* bo = (const float*)d_in[8];

  u16* ws = (u16*)d_ws;

  prepx_k<<<dim3(CONV_BLKS + 256), dim3(256), 0, stream>>>(
      x, Wq, Wk, Wv, Wo, bq, bk, bv, bo, ws);
  qkvattn_k<<<dim3(NWINS * NHEAD), dim3(256), 0, stream>>>(ws);
  gemm_k<<<dim3(GEMM_BLKS), dim3(256), 0, stream>>>(
      ws, OFF_OBUF, OFF_WOT, OFF_BIAS2, (float*)d_out, DM);
}

// Round 11
// 245.550 us; speedup vs baseline: 1.3400x; 1.0019x over previous
//
#include <hip/hip_runtime.h>

typedef unsigned short u16;
typedef __attribute__((ext_vector_type(4))) float f32x4;
typedef __attribute__((ext_vector_type(8))) short short8;
typedef __attribute__((ext_vector_type(4))) short short4v;

#define WIN_SZ 100
#define NWIN 41
#define NBATCH 8
#define SEQ 4096
#define DM 512
#define NHEAD 8
#define KD 64
#define NWINS (NBATCH * NWIN)    // 328
#define MROWS (NWINS * WIN_SZ)   // 32800
#define MBLKS 257                // ceil(32800/128)
#define TOKPB (NWIN * WIN_SZ)    // 4100
#define NQKV 1536
#define CONV_GRID 2048                          // grid-stride conv blocks (G11)
#define GEMM_BLKS (((MBLKS + 7) / 8) * 32)      // 33 panel-groups * 32 = 1056

// ws layout (u16 element offsets)
#define OFF_XBF   0u
#define OFF_OBUF  16793600u                 // + MROWS*DM
#define OFF_WQKVT 33587200u                 // + MROWS*DM
#define OFF_WOT   34373632u                 // + NQKV*DM
#define OFF_ZBLK  34635776u                 // + DM*DM
#define OFF_BIAS  34636032u                 // + 256   (1536 fp32 qkv bias)
#define OFF_BIAS2 34639104u                 // + 3072  (512 fp32 bo)

// 16x16x16 bf16 MFMA (K=16): B-frag k-slice (l>>4)*4+e matches the in-register
// P layout after swapped-QK^T, so PV needs no cross-lane P redistribution.
// NOTE: no __has_builtin guard — it returns false in the HOST pass of hipcc
// (aux-target builtins are callable there but not listed), which broke r6/r7.
#define MFMA16(a, b, c) __builtin_amdgcn_mfma_f32_16x16x16bf16_1k(a, b, c, 0, 0, 0)

__device__ __forceinline__ u16 f2bf(float f) {
  union { float f; unsigned i; } v; v.f = f;
  unsigned r = (v.i + 0x7fffu + ((v.i >> 16) & 1u)) >> 16;
  return (u16)r;
}

// non-temporal 8B store (final outputs / cross-XCD hand-offs: keep L2 clean)
__device__ __forceinline__ void nt_store_u64(u16* p, uint2 v) {
  __builtin_nontemporal_store(*(const unsigned long long*)&v,
                              (unsigned long long*)p);
}

// async global->LDS, 16B per lane; lds base wave-uniform (HW adds lane*16)
__device__ __forceinline__ void gl2lds16(const void* g, void* lds) {
  __builtin_amdgcn_global_load_lds(
      (const __attribute__((address_space(1))) void*)g,
      (__attribute__((address_space(3))) void*)lds, 16, 0, 0);
}

// ---------- merged: x fp32->bf16 window gather (blocks [0,CONV_GRID)) ----------
// ---------- + weight transposes / biases / zblk (blocks [CONV_GRID, +256)) ----
__global__ void prepx_k(const float* __restrict__ x,
                        const float* __restrict__ Wq, const float* __restrict__ Wk,
                        const float* __restrict__ Wv, const float* __restrict__ Wo,
                        const float* __restrict__ bq, const float* __restrict__ bk,
                        const float* __restrict__ bv, const float* __restrict__ bo,
                        u16* __restrict__ ws) {
  __shared__ u16 tile[64][65];
  const int t = threadIdx.x;
  if (blockIdx.x < CONV_GRID) {
    // ---- convx half: grid-stride, 32B in / 16B out per thread-iter ----
    // NT loads: x is read exactly once; keep L2 for xbf (re-read by qkvattn).
    // (f32x4 is a clang ext_vector — HIP's float4 class is rejected by the
    //  nontemporal builtins; that was round 10's compile error.)
    u16* xbf = ws + OFF_XBF;
    const int total = MROWS * 64;               // 32B-group count
    for (int i = blockIdx.x * 256 + t; i < total; i += CONV_GRID * 256) {
      int m = i >> 6;
      int c8 = (i & 63) * 8;
      int b = m / TOKPB, tk = m - b * TOKPB;
      u16 o[8] = {0, 0, 0, 0, 0, 0, 0, 0};
      if (tk < SEQ) {
        const float* src = x + (size_t)(b * SEQ + tk) * DM + c8;
        f32x4 v0 = __builtin_nontemporal_load((const f32x4*)src);
        f32x4 v1 = __builtin_nontemporal_load((const f32x4*)(src + 4));
        o[0] = f2bf(v0.x); o[1] = f2bf(v0.y); o[2] = f2bf(v0.z); o[3] = f2bf(v0.w);
        o[4] = f2bf(v1.x); o[5] = f2bf(v1.y); o[6] = f2bf(v1.z); o[7] = f2bf(v1.w);
      }
      *(uint4*)(xbf + (size_t)m * DM + c8) = *(const uint4*)o;
    }
    return;
  }
  // ---- prep half: p -> (bx, by, z) of the old dim3(8,8,4) grid ----
  const int p = blockIdx.x - CONV_GRID;
  const int z = p >> 6, by = (p >> 3) & 7, bx = p & 7;
  const float* src = (z == 0) ? Wq : (z == 1) ? Wk : (z == 2) ? Wv : Wo;
  u16* dst = (z < 3) ? (ws + OFF_WQKVT + (unsigned)z * 512u * 512u)
                     : (ws + OFF_WOT);
  const int k0 = by * 64, n0 = bx * 64;
  const int c = t & 63, r4 = t >> 6;
#pragma unroll
  for (int pp = 0; pp < 16; ++pp) {
    int r = pp * 4 + r4;
    tile[r][c] = f2bf(src[(size_t)(k0 + r) * 512 + n0 + c]);
  }
  __syncthreads();
#pragma unroll
  for (int pp = 0; pp < 16; ++pp) {
    int r = pp * 4 + r4;                       // n index within tile
    dst[(size_t)(n0 + r) * 512 + k0 + c] = tile[c][r];
  }
  if (bx == 0 && by == 0) {
    float* biasF = (float*)(ws + OFF_BIAS);
    float* biasO = (float*)(ws + OFF_BIAS2);
    for (int j = t; j < 512; j += 256) {
      if (z == 0) biasF[j] = bq[j];
      else if (z == 1) biasF[512 + j] = bk[j];
      else if (z == 2) biasF[1024 + j] = bv[j];
      else biasO[j] = bo[j];
    }
    if (z == 3 && t < 128) ws[OFF_ZBLK + t] = 0;
  }
}

// -------------- fused QKV projection + attention, one block per (win, head) --------------
#define QKS 72   // Qs/Ks stride
#define PS 136   // Vt stride
// LDS phase-union (u16 elems), total 24832 (49664 B -> 3 blocks/CU):
//   phase1 (staging, dies at post-loop barrier): Xs [0,7168) + Wsl [7168,19456)
//   phase2+: Vt [0,8704) | Qs [8704,16768) | Ks [16768,24832)
//   (no P buffer: softmax->PV stays in registers via swapped QK^T + K=16 PV)
#define SM_ELEMS 24832

__global__ __launch_bounds__(256, 3)
void qkvattn_k(const u16* __restrict__ ws) {
  __shared__ u16 smem[SM_ELEMS];
  u16* Xs  = smem;              // 112 x 64 (column-slot XOR-swizzled per row)
  u16* Wsl = smem + 7168;       // 192 x 64 (column-slot XOR-swizzled per row)
  u16* Vt  = smem;              // 64 x 136
  u16* Qs  = smem + 8704;       // 112 x 72
  u16* Ks  = smem + 16768;      // 112 x 72

  // XCD-locality mapping (T1): all 8 heads of a window share f mod 8 (same
  // XCD L2) and are consecutive in that XCD's stream -> X tile staged 8x
  // while L2-hot. f = (win>>3)*64 + h*8 + (win&7); bijective over 2624.
  const int f = blockIdx.x;
  const int h = (f >> 3) & 7;
  const int win = ((f >> 6) << 3) + (f & 7);

  const int t = threadIdx.x, w = t >> 6, l = t & 63;
  const int q = l >> 4, cl = l & 15;
  // Bank-conflict fix (G4/T2, m173 pattern): pre-swizzle the GLOBAL source
  // column; read-side XOR undoes it. 128B row stride otherwise 16-way conflicts.
  const int lsw = (((t & 7) ^ ((t >> 3) & 7)) * 8);

  // staging source offsets (column pre-swizzled)
  unsigned xoff[4];
#pragma unroll
  for (int i = 0; i < 4; ++i) {
    int m = i * 32 + (t >> 3);
    xoff[i] = (m < WIN_SZ)
                  ? (OFF_XBF + (unsigned)(win * WIN_SZ + m) * DM + lsw)
                  : OFF_ZBLK;
  }
  unsigned woff[6];
#pragma unroll
  for (int i = 0; i < 6; ++i) {
    int g = i * 32 + (t >> 3);
    unsigned nrow = (unsigned)(g >> 6) * 512u + (unsigned)h * 64u + (g & 63);
    woff[i] = OFF_WQKVT + nrow * DM + lsw;
  }

  // ---- phase 1: QKV projection. wave w owns n-tiles {3w,3w+1,3w+2} of 12 ----
  f32x4 acc_p[7][3] = {};
  for (int k0 = 0; k0 < DM; k0 += 64) {
    __syncthreads();
#pragma unroll
    for (int i = 0; i < 4; ++i)
      if (i * 32 + w * 8 < 112)   // wave-uniform
        gl2lds16(ws + xoff[i] + (xoff[i] == OFF_ZBLK ? 0u : (unsigned)k0),
                 &Xs[(i * 32 + w * 8) * 64]);
#pragma unroll
    for (int i = 0; i < 6; ++i)
      gl2lds16(ws + woff[i] + k0, &Wsl[(i * 32 + w * 8) * 64]);
    __syncthreads();
#pragma unroll
    for (int ks = 0; ks < 2; ++ks) {
      const int ko = ks * 32 + q * 8;
      const int koS = ko ^ ((cl & 7) << 3);   // read-side swizzle
      short8 af[7], bf[3];
#pragma unroll
      for (int mt = 0; mt < 7; ++mt)
        af[mt] = *(const short8*)&Xs[(mt * 16 + cl) * 64 + koS];
#pragma unroll
      for (int ntl = 0; ntl < 3; ++ntl)
        bf[ntl] = *(const short8*)&Wsl[((3 * w + ntl) * 16 + cl) * 64 + koS];
      __builtin_amdgcn_s_setprio(1);
#pragma unroll
      for (int mt = 0; mt < 7; ++mt)
#pragma unroll
        for (int ntl = 0; ntl < 3; ++ntl)
          acc_p[mt][ntl] = __builtin_amdgcn_mfma_f32_16x16x32_bf16(
              af[mt], bf[ntl], acc_p[mt][ntl], 0, 0, 0);
      __builtin_amdgcn_s_setprio(0);
    }
  }
  __syncthreads();  // staging reads drained; Vt/Qs/Ks may now overwrite

  // ---- phase 2: accs (+bias) -> Qs / Ks / Vt ----
  {
    const float* biasF = (const float*)(ws + OFF_BIAS);
#pragma unroll
    for (int ntl = 0; ntl < 3; ++ntl) {
      const int nt = 3 * w + ntl;                      // wave-uniform
      const int cw = (nt & 3) * 16 + cl;               // col within Q/K/V
      const float bb = biasF[(nt >> 2) * 512 + h * 64 + cw];
      if (nt < 8) {
        u16* dst = (nt < 4) ? Qs : Ks;
#pragma unroll
        for (int mt = 0; mt < 7; ++mt)
#pragma unroll
          for (int r = 0; r < 4; ++r) {
            const int tok = mt * 16 + q * 4 + r;
            dst[tok * QKS + cw] = f2bf(acc_p[mt][ntl][r] + bb);
          }
      } else {
        // V: r-index is contiguous in Vt -> pack 4 u16 into one b64 write
#pragma unroll
        for (int mt = 0; mt < 7; ++mt) {
          u16 pkv[4];
#pragma unroll
          for (int r = 0; r < 4; ++r) pkv[r] = f2bf(acc_p[mt][ntl][r] + bb);
          *(uint2*)&Vt[cw * PS + mt * 16 + q * 4] = *(const uint2*)pkv;
        }
      }
    }
    // no Vt pad zeroing needed: PV only reads tokens 0..111 (K=16 tiles),
    // and tokens 100..111 are killed by P=0 from the softmax mask.
  }
  __syncthreads();

  // ---- phase 3: S^T = K Q^T (swapped operands). wave w owns Q-tiles {w, w+4} ----
  // D layout: row = token = nt*16 + q*4 + r (A=K side), col = Q-row = mt*16 + cl.
  const int nmt = (w < 3) ? 2 : 1;
  const int mt0 = w, mt1 = w + 4;

  f32x4 accs[2][7];
#pragma unroll
  for (int im = 0; im < 2; ++im) {
    if (im < nmt) {
      const int mt = (im == 0) ? mt0 : mt1;
      const int ar = (mt * 16 + cl) * QKS + q * 8;
      short8 qa0 = *(const short8*)&Qs[ar];
      short8 qa1 = *(const short8*)&Qs[ar + 32];
      __builtin_amdgcn_s_setprio(1);
#pragma unroll
      for (int nt = 0; nt < 7; ++nt) {
        const int br = (nt * 16 + cl) * QKS + q * 8;
        short8 kb0 = *(const short8*)&Ks[br];
        short8 kb1 = *(const short8*)&Ks[br + 32];
        f32x4 c = {};
        c = __builtin_amdgcn_mfma_f32_16x16x32_bf16(kb0, qa0, c, 0, 0, 0);
        c = __builtin_amdgcn_mfma_f32_16x16x32_bf16(kb1, qa1, c, 0, 0, 0);
        accs[im][nt] = c;
      }
      __builtin_amdgcn_s_setprio(0);
    }
  }

  // softmax over tokens (in-lane 28 values + 2 shfl over the q-group),
  // then pack P to bf16 pairs in-register: pk[im][nt][j] holds tokens
  // nt*16 + 4q + {2j, 2j+1} -- exactly the 16x16x16 B-frag k-slice.
  const float scale = 0.125f;  // 1/sqrt(64)
  unsigned pk[2][7][2];
#pragma unroll
  for (int im = 0; im < 2; ++im) {
    if (im < nmt) {
      float mx = -1e30f;
#pragma unroll
      for (int nt = 0; nt < 7; ++nt)
#pragma unroll
        for (int r = 0; r < 4; ++r) {
          float s = accs[im][nt][r] * scale;
          accs[im][nt][r] = s;
          if ((nt < 6) || (q == 0)) mx = fmaxf(mx, s);   // token<100 valid
        }
      mx = fmaxf(mx, __shfl_xor(mx, 16, 64));
      mx = fmaxf(mx, __shfl_xor(mx, 32, 64));
      float sum = 0.f;
#pragma unroll
      for (int nt = 0; nt < 7; ++nt)
#pragma unroll
        for (int r = 0; r < 4; ++r) {
          bool valid = (nt < 6) || (q == 0);
          float e = valid ? __expf(accs[im][nt][r] - mx) : 0.f;
          accs[im][nt][r] = e;
          sum += e;
        }
      sum += __shfl_xor(sum, 16, 64);
      sum += __shfl_xor(sum, 32, 64);
      float inv = 1.0f / sum;
#pragma unroll
      for (int nt = 0; nt < 7; ++nt) {
        pk[im][nt][0] = (unsigned)f2bf(accs[im][nt][0] * inv) |
                        ((unsigned)f2bf(accs[im][nt][1] * inv) << 16);
        pk[im][nt][1] = (unsigned)f2bf(accs[im][nt][2] * inv) |
                        ((unsigned)f2bf(accs[im][nt][3] * inv) << 16);
      }
    }
  }
  // no barrier needed: PV reads only Vt (written before the phase-2 barrier)

  // ---- phase 4: O^T = V^T P^T via K=16 MFMA, P straight from registers ----
  // D: col = Q-row = mt*16+cl, row = kd = vt*16 + q*4 + r.
  f32x4 acco[2][4] = {};
  __builtin_amdgcn_s_setprio(1);
#pragma unroll
  for (int vt = 0; vt < 4; ++vt) {
#pragma unroll
    for (int nt = 0; nt < 7; ++nt) {
      short4v av = *(const short4v*)&Vt[(vt * 16 + cl) * PS + nt * 16 + q * 4];
      union { unsigned u[2]; short4v s; } b0, b1;
      b0.u[0] = pk[0][nt][0]; b0.u[1] = pk[0][nt][1];
      acco[0][vt] = MFMA16(av, b0.s, acco[0][vt]);
      if (nmt == 2) {
        b1.u[0] = pk[1][nt][0]; b1.u[1] = pk[1][nt][1];
        acco[1][vt] = MFMA16(av, b1.s, acco[1][vt]);
      }
    }
  }
  __builtin_amdgcn_s_setprio(0);

  // ---- epilogue: packed 8B NT stores (reader is on a different XCD) ----
  u16* obuf = (u16*)(ws + OFF_OBUF);
  const size_t orow0 = (size_t)win * WIN_SZ;
#pragma unroll
  for (int im = 0; im < 2; ++im) {
    if (im < nmt) {
      const int mt = (im == 0) ? mt0 : mt1;
      const int row = mt * 16 + cl;
      if (row < WIN_SZ) {
#pragma unroll
        for (int vt = 0; vt < 4; ++vt) {
          u16 ov[4];
#pragma unroll
          for (int r = 0; r < 4; ++r) ov[r] = f2bf(acco[im][vt][r]);
          nt_store_u64(&obuf[(orow0 + row) * DM + h * KD + vt * 16 + q * 4],
                       *(const uint2*)ov);
        }
      }
    }
  }
}

// ---------------- GEMM: C[M,N] = A[M,512] @ Bt[N,512]^T + bias (fp32 out) ----------------
__global__ __launch_bounds__(256, 4)
void gemm_k(const u16* __restrict__ ws, unsigned aoff0, unsigned btoff,
            unsigned biasoff, float* __restrict__ Cout, int Ntot) {
  __shared__ u16 Alds[128 * 64];
  __shared__ u16 Blds[128 * 64];

  // XCD-locality mapping (T1): the 4 n-blocks sharing an A-panel get ids
  // differing by multiples of 8 (same XCD) and consecutive in that XCD's
  // stream -> the 131KB A-panel is read from HBM once, L2-hit 3x.
  // f = (p>>3)*32 + nb*8 + (p&7); panels padded to 264 (28 dummy blocks).
  const int f = blockIdx.x;
  const int nb = (f >> 3) & 3;
  const int p = ((f >> 5) << 3) + (f & 7);
  if (p >= MBLKS) return;

  const int t = threadIdx.x;
  const int w = t >> 6;
  const int l = t & 63;
  const int m0 = p * 128, n0 = nb * 128;
  const int lr = t >> 3;
  // same G4/T2 swizzle as qkvattn_k phase 1 (128B row stride)
  const int lsw = (((t & 7) ^ ((t >> 3) & 7)) * 8);

  unsigned aoff[4], boff[4];
#pragma unroll
  for (int i = 0; i < 4; ++i) {
    int m = m0 + i * 32 + lr;
    aoff[i] = (m < MROWS) ? (aoff0 + (unsigned)m * DM + lsw) : OFF_ZBLK;
    boff[i] = btoff + (unsigned)(n0 + i * 32 + lr) * DM + lsw;
  }

  f32x4 acc[4][4] = {};
  const int wm = (w & 1) * 64;
  const int wn = (w >> 1) * 64;
  const int q = l >> 4, cl = l & 15;

  for (int k0 = 0; k0 < DM; k0 += 64) {
    __syncthreads();
#pragma unroll
    for (int i = 0; i < 4; ++i) {
      gl2lds16(ws + aoff[i] + (aoff[i] == OFF_ZBLK ? 0u : (unsigned)k0),
               &Alds[(i * 32 + w * 8) * 64]);
      gl2lds16(ws + boff[i] + k0, &Blds[(i * 32 + w * 8) * 64]);
    }
    __syncthreads();
#pragma unroll
    for (int ks = 0; ks < 2; ++ks) {
      short8 av[4], bv_[4];
      const int ko = ks * 32 + q * 8;
      const int koS = ko ^ ((cl & 7) << 3);   // read-side swizzle
#pragma unroll
      for (int mi = 0; mi < 4; ++mi)
        av[mi] = *(const short8*)&Alds[(wm + mi * 16 + cl) * 64 + koS];
#pragma unroll
      for (int ni = 0; ni < 4; ++ni)
        bv_[ni] = *(const short8*)&Blds[(wn + ni * 16 + cl) * 64 + koS];
      __builtin_amdgcn_s_setprio(1);
#pragma unroll
      for (int mi = 0; mi < 4; ++mi)
#pragma unroll
        for (int ni = 0; ni < 4; ++ni)
          acc[mi][ni] = __builtin_amdgcn_mfma_f32_16x16x32_bf16(
              av[mi], bv_[ni], acc[mi][ni], 0, 0, 0);
      __builtin_amdgcn_s_setprio(0);
    }
  }

  const float* biasF = (const float*)(ws + biasoff);
#pragma unroll
  for (int mi = 0; mi < 4; ++mi) {
#pragma unroll
    for (int ni = 0; ni < 4; ++ni) {
      int col = n0 + wn + ni * 16 + cl;
      float bb = biasF[col];
#pragma unroll
      for (int r = 0; r < 4; ++r) {
        int row = m0 + wm + mi * 16 + q * 4 + r;
        if (row < MROWS)
          __builtin_nontemporal_store(acc[mi][ni][r] + bb,
                                      &Cout[(size_t)row * Ntot + col]);
      }
    }
  }
}

extern "C" void kernel_launch(void* const* d_in, const int* in_sizes, int n_in,
                              void* d_out, int out_size, void* d_ws, size_t ws_size,
                              hipStream_t stream) {
  const float* x  = (const float*)d_in[0];
  const float* Wq = (const float*)d_in[1];
  const float* bq = (const float*)d_in[2];
  const float* Wk = (const float*)d_in[3];
  const float* bk = (const float*)d_in[4];
  const float* Wv = (const float*)d_in[5];
  const float* bv = (const float*)d_in[6];
  const float* Wo = (const float*)d_in[7];
  const float* bo = (const float*)d_in[8];

  u16* ws = (u16*)d_ws;

  prepx_k<<<dim3(CONV_GRID + 256), dim3(256), 0, stream>>>(
      x, Wq, Wk, Wv, Wo, bq, bk, bv, bo, ws);
  qkvattn_k<<<dim3(NWINS * NHEAD), dim3(256), 0, stream>>>(ws);
  gemm_k<<<dim3(GEMM_BLKS), dim3(256), 0, stream>>>(
      ws, OFF_OBUF, OFF_WOT, OFF_BIAS2, (float*)d_out, DM);
}

// Round 12
// 239.424 us; speedup vs baseline: 1.3742x; 1.0256x over previous
//
#include <hip/hip_runtime.h>

typedef unsigned short u16;
typedef __attribute__((ext_vector_type(4))) float f32x4;
typedef __attribute__((ext_vector_type(8))) short short8;
typedef __attribute__((ext_vector_type(4))) short short4v;

#define WIN_SZ 100
#define NWIN 41
#define NBATCH 8
#define SEQ 4096
#define DM 512
#define NHEAD 8
#define KD 64
#define NWINS (NBATCH * NWIN)    // 328
#define MROWS (NWINS * WIN_SZ)   // 32800
#define MBLKS 257                // ceil(32800/128)
#define TOKPB (NWIN * WIN_SZ)    // 4100
#define NQKV 1536
#define CONV_GRID 2048                          // grid-stride conv blocks (G11)
#define GEMM_BLKS (((MBLKS + 7) / 8) * 32)      // 33 panel-groups * 32 = 1056

// ws layout (u16 element offsets)
#define OFF_XBF   0u
#define OFF_OBUF  16793600u                 // + MROWS*DM
#define OFF_WQKVT 33587200u                 // + MROWS*DM
#define OFF_WOT   34373632u                 // + NQKV*DM
#define OFF_ZBLK  34635776u                 // + DM*DM
#define OFF_BIAS  34636032u                 // + 256   (1536 fp32 qkv bias)
#define OFF_BIAS2 34639104u                 // + 3072  (512 fp32 bo)

// 16x16x16 bf16 MFMA (K=16): B-frag k-slice (l>>4)*4+e matches the in-register
// P layout after swapped-QK^T, so PV needs no cross-lane P redistribution.
// NOTE: no __has_builtin guard — it returns false in the HOST pass of hipcc
// (aux-target builtins are callable there but not listed), which broke r6/r7.
#define MFMA16(a, b, c) __builtin_amdgcn_mfma_f32_16x16x16bf16_1k(a, b, c, 0, 0, 0)

__device__ __forceinline__ u16 f2bf(float f) {
  union { float f; unsigned i; } v; v.f = f;
  unsigned r = (v.i + 0x7fffu + ((v.i >> 16) & 1u)) >> 16;
  return (u16)r;
}

// async global->LDS, 16B per lane; lds base wave-uniform (HW adds lane*16)
__device__ __forceinline__ void gl2lds16(const void* g, void* lds) {
  __builtin_amdgcn_global_load_lds(
      (const __attribute__((address_space(1))) void*)g,
      (__attribute__((address_space(3))) void*)lds, 16, 0, 0);
}

// ---------- merged: x fp32->bf16 window gather (blocks [0,CONV_GRID)) ----------
// ---------- + weight transposes / biases / zblk (blocks [CONV_GRID, +256)) ----
__global__ void prepx_k(const float* __restrict__ x,
                        const float* __restrict__ Wq, const float* __restrict__ Wk,
                        const float* __restrict__ Wv, const float* __restrict__ Wo,
                        const float* __restrict__ bq, const float* __restrict__ bk,
                        const float* __restrict__ bv, const float* __restrict__ bo,
                        u16* __restrict__ ws) {
  __shared__ u16 tile[64][65];
  const int t = threadIdx.x;
  if (blockIdx.x < CONV_GRID) {
    // ---- convx half: grid-stride, 32B in / 16B out per thread-iter ----
    // NT loads: x is read exactly once; keep L2 for xbf (re-read by qkvattn).
    u16* xbf = ws + OFF_XBF;
    const int total = MROWS * 64;               // 32B-group count
    for (int i = blockIdx.x * 256 + t; i < total; i += CONV_GRID * 256) {
      int m = i >> 6;
      int c8 = (i & 63) * 8;
      int b = m / TOKPB, tk = m - b * TOKPB;
      u16 o[8] = {0, 0, 0, 0, 0, 0, 0, 0};
      if (tk < SEQ) {
        const float* src = x + (size_t)(b * SEQ + tk) * DM + c8;
        f32x4 v0 = __builtin_nontemporal_load((const f32x4*)src);
        f32x4 v1 = __builtin_nontemporal_load((const f32x4*)(src + 4));
        o[0] = f2bf(v0.x); o[1] = f2bf(v0.y); o[2] = f2bf(v0.z); o[3] = f2bf(v0.w);
        o[4] = f2bf(v1.x); o[5] = f2bf(v1.y); o[6] = f2bf(v1.z); o[7] = f2bf(v1.w);
      }
      *(uint4*)(xbf + (size_t)m * DM + c8) = *(const uint4*)o;
    }
    return;
  }
  // ---- prep half: p -> (bx, by, z) of the old dim3(8,8,4) grid ----
  const int p = blockIdx.x - CONV_GRID;
  const int z = p >> 6, by = (p >> 3) & 7, bx = p & 7;
  const float* src = (z == 0) ? Wq : (z == 1) ? Wk : (z == 2) ? Wv : Wo;
  u16* dst = (z < 3) ? (ws + OFF_WQKVT + (unsigned)z * 512u * 512u)
                     : (ws + OFF_WOT);
  const int k0 = by * 64, n0 = bx * 64;
  const int c = t & 63, r4 = t >> 6;
#pragma unroll
  for (int pp = 0; pp < 16; ++pp) {
    int r = pp * 4 + r4;
    tile[r][c] = f2bf(src[(size_t)(k0 + r) * 512 + n0 + c]);
  }
  __syncthreads();
#pragma unroll
  for (int pp = 0; pp < 16; ++pp) {
    int r = pp * 4 + r4;                       // n index within tile
    dst[(size_t)(n0 + r) * 512 + k0 + c] = tile[c][r];
  }
  if (bx == 0 && by == 0) {
    float* biasF = (float*)(ws + OFF_BIAS);
    float* biasO = (float*)(ws + OFF_BIAS2);
    for (int j = t; j < 512; j += 256) {
      if (z == 0) biasF[j] = bq[j];
      else if (z == 1) biasF[512 + j] = bk[j];
      else if (z == 2) biasF[1024 + j] = bv[j];
      else biasO[j] = bo[j];
    }
    if (z == 3 && t < 128) ws[OFF_ZBLK + t] = 0;
  }
}

// -------------- fused QKV projection + attention, one block per (win, head) --------------
#define QKS 72   // Qs/Ks stride
#define PS 136   // Vt stride
// LDS phase-union (u16 elems), total 24832 (49664 B -> 3 blocks/CU):
//   phase1 (staging, dies at post-loop barrier): Xs [0,7168) + Wsl [7168,19456)
//   phase2+: Vt [0,8704) | Qs [8704,16768) | Ks [16768,24832)
//   (no P buffer: softmax->PV stays in registers via swapped QK^T + K=16 PV)
#define SM_ELEMS 24832

__global__ __launch_bounds__(256, 3)
void qkvattn_k(const u16* __restrict__ ws) {
  __shared__ u16 smem[SM_ELEMS];
  u16* Xs  = smem;              // 112 x 64 (column-slot XOR-swizzled per row)
  u16* Wsl = smem + 7168;       // 192 x 64 (column-slot XOR-swizzled per row)
  u16* Vt  = smem;              // 64 x 136
  u16* Qs  = smem + 8704;       // 112 x 72
  u16* Ks  = smem + 16768;      // 112 x 72

  // XCD-locality mapping (T1): all 8 heads of a window share f mod 8 (same
  // XCD L2) and are consecutive in that XCD's stream -> X tile staged 8x
  // while L2-hot. f = (win>>3)*64 + h*8 + (win&7); bijective over 2624.
  const int f = blockIdx.x;
  const int h = (f >> 3) & 7;
  const int win = ((f >> 6) << 3) + (f & 7);

  const int t = threadIdx.x, w = t >> 6, l = t & 63;
  const int q = l >> 4, cl = l & 15;
  // Bank-conflict fix (G4/T2, m173 pattern): pre-swizzle the GLOBAL source
  // column; read-side XOR undoes it. 128B row stride otherwise 16-way conflicts.
  const int lsw = (((t & 7) ^ ((t >> 3) & 7)) * 8);

  // staging source offsets (column pre-swizzled)
  unsigned xoff[4];
#pragma unroll
  for (int i = 0; i < 4; ++i) {
    int m = i * 32 + (t >> 3);
    xoff[i] = (m < WIN_SZ)
                  ? (OFF_XBF + (unsigned)(win * WIN_SZ + m) * DM + lsw)
                  : OFF_ZBLK;
  }
  unsigned woff[6];
#pragma unroll
  for (int i = 0; i < 6; ++i) {
    int g = i * 32 + (t >> 3);
    unsigned nrow = (unsigned)(g >> 6) * 512u + (unsigned)h * 64u + (g & 63);
    woff[i] = OFF_WQKVT + nrow * DM + lsw;
  }

  // ---- phase 1: QKV projection. wave w owns n-tiles {3w,3w+1,3w+2} of 12 ----
  f32x4 acc_p[7][3] = {};
  for (int k0 = 0; k0 < DM; k0 += 64) {
    __syncthreads();
#pragma unroll
    for (int i = 0; i < 4; ++i)
      if (i * 32 + w * 8 < 112)   // wave-uniform
        gl2lds16(ws + xoff[i] + (xoff[i] == OFF_ZBLK ? 0u : (unsigned)k0),
                 &Xs[(i * 32 + w * 8) * 64]);
#pragma unroll
    for (int i = 0; i < 6; ++i)
      gl2lds16(ws + woff[i] + k0, &Wsl[(i * 32 + w * 8) * 64]);
    __syncthreads();
#pragma unroll
    for (int ks = 0; ks < 2; ++ks) {
      const int ko = ks * 32 + q * 8;
      const int koS = ko ^ ((cl & 7) << 3);   // read-side swizzle
      short8 af[7], bf[3];
#pragma unroll
      for (int mt = 0; mt < 7; ++mt)
        af[mt] = *(const short8*)&Xs[(mt * 16 + cl) * 64 + koS];
#pragma unroll
      for (int ntl = 0; ntl < 3; ++ntl)
        bf[ntl] = *(const short8*)&Wsl[((3 * w + ntl) * 16 + cl) * 64 + koS];
      __builtin_amdgcn_s_setprio(1);
#pragma unroll
      for (int mt = 0; mt < 7; ++mt)
#pragma unroll
        for (int ntl = 0; ntl < 3; ++ntl)
          acc_p[mt][ntl] = __builtin_amdgcn_mfma_f32_16x16x32_bf16(
              af[mt], bf[ntl], acc_p[mt][ntl], 0, 0, 0);
      __builtin_amdgcn_s_setprio(0);
    }
  }
  __syncthreads();  // staging reads drained; Vt/Qs/Ks may now overwrite

  // ---- phase 2: accs (+bias) -> Qs / Ks / Vt ----
  {
    const float* biasF = (const float*)(ws + OFF_BIAS);
#pragma unroll
    for (int ntl = 0; ntl < 3; ++ntl) {
      const int nt = 3 * w + ntl;                      // wave-uniform
      const int cw = (nt & 3) * 16 + cl;               // col within Q/K/V
      const float bb = biasF[(nt >> 2) * 512 + h * 64 + cw];
      if (nt < 8) {
        u16* dst = (nt < 4) ? Qs : Ks;
#pragma unroll
        for (int mt = 0; mt < 7; ++mt)
#pragma unroll
          for (int r = 0; r < 4; ++r) {
            const int tok = mt * 16 + q * 4 + r;
            dst[tok * QKS + cw] = f2bf(acc_p[mt][ntl][r] + bb);
          }
      } else {
        // V: r-index is contiguous in Vt -> pack 4 u16 into one b64 write
#pragma unroll
        for (int mt = 0; mt < 7; ++mt) {
          u16 pkv[4];
#pragma unroll
          for (int r = 0; r < 4; ++r) pkv[r] = f2bf(acc_p[mt][ntl][r] + bb);
          *(uint2*)&Vt[cw * PS + mt * 16 + q * 4] = *(const uint2*)pkv;
        }
      }
    }
    // no Vt pad zeroing needed: PV only reads tokens 0..111 (K=16 tiles),
    // and tokens 100..111 are killed by P=0 from the softmax mask.
  }
  __syncthreads();

  // ---- phase 3: S^T = K Q^T (swapped operands). wave w owns Q-tiles {w, w+4} ----
  // D layout: row = token = nt*16 + q*4 + r (A=K side), col = Q-row = mt*16 + cl.
  const int nmt = (w < 3) ? 2 : 1;
  const int mt0 = w, mt1 = w + 4;

  f32x4 accs[2][7];
#pragma unroll
  for (int im = 0; im < 2; ++im) {
    if (im < nmt) {
      const int mt = (im == 0) ? mt0 : mt1;
      const int ar = (mt * 16 + cl) * QKS + q * 8;
      short8 qa0 = *(const short8*)&Qs[ar];
      short8 qa1 = *(const short8*)&Qs[ar + 32];
      __builtin_amdgcn_s_setprio(1);
#pragma unroll
      for (int nt = 0; nt < 7; ++nt) {
        const int br = (nt * 16 + cl) * QKS + q * 8;
        short8 kb0 = *(const short8*)&Ks[br];
        short8 kb1 = *(const short8*)&Ks[br + 32];
        f32x4 c = {};
        c = __builtin_amdgcn_mfma_f32_16x16x32_bf16(kb0, qa0, c, 0, 0, 0);
        c = __builtin_amdgcn_mfma_f32_16x16x32_bf16(kb1, qa1, c, 0, 0, 0);
        accs[im][nt] = c;
      }
      __builtin_amdgcn_s_setprio(0);
    }
  }

  // softmax over tokens (in-lane 28 values + 2 shfl over the q-group),
  // then pack P to bf16 pairs in-register: pk[im][nt][j] holds tokens
  // nt*16 + 4q + {2j, 2j+1} -- exactly the 16x16x16 B-frag k-slice.
  const float scale = 0.125f;  // 1/sqrt(64)
  unsigned pk[2][7][2];
#pragma unroll
  for (int im = 0; im < 2; ++im) {
    if (im < nmt) {
      float mx = -1e30f;
#pragma unroll
      for (int nt = 0; nt < 7; ++nt)
#pragma unroll
        for (int r = 0; r < 4; ++r) {
          float s = accs[im][nt][r] * scale;
          accs[im][nt][r] = s;
          if ((nt < 6) || (q == 0)) mx = fmaxf(mx, s);   // token<100 valid
        }
      mx = fmaxf(mx, __shfl_xor(mx, 16, 64));
      mx = fmaxf(mx, __shfl_xor(mx, 32, 64));
      float sum = 0.f;
#pragma unroll
      for (int nt = 0; nt < 7; ++nt)
#pragma unroll
        for (int r = 0; r < 4; ++r) {
          bool valid = (nt < 6) || (q == 0);
          float e = valid ? __expf(accs[im][nt][r] - mx) : 0.f;
          accs[im][nt][r] = e;
          sum += e;
        }
      sum += __shfl_xor(sum, 16, 64);
      sum += __shfl_xor(sum, 32, 64);
      float inv = 1.0f / sum;
#pragma unroll
      for (int nt = 0; nt < 7; ++nt) {
        pk[im][nt][0] = (unsigned)f2bf(accs[im][nt][0] * inv) |
                        ((unsigned)f2bf(accs[im][nt][1] * inv) << 16);
        pk[im][nt][1] = (unsigned)f2bf(accs[im][nt][2] * inv) |
                        ((unsigned)f2bf(accs[im][nt][3] * inv) << 16);
      }
    }
  }
  // no barrier needed: PV reads only Vt (written before the phase-2 barrier)

  // ---- phase 4: O^T = V^T P^T via K=16 MFMA, P straight from registers ----
  // D: col = Q-row = mt*16+cl, row = kd = vt*16 + q*4 + r.
  f32x4 acco[2][4] = {};
  __builtin_amdgcn_s_setprio(1);
#pragma unroll
  for (int vt = 0; vt < 4; ++vt) {
#pragma unroll
    for (int nt = 0; nt < 7; ++nt) {
      short4v av = *(const short4v*)&Vt[(vt * 16 + cl) * PS + nt * 16 + q * 4];
      union { unsigned u[2]; short4v s; } b0, b1;
      b0.u[0] = pk[0][nt][0]; b0.u[1] = pk[0][nt][1];
      acco[0][vt] = MFMA16(av, b0.s, acco[0][vt]);
      if (nmt == 2) {
        b1.u[0] = pk[1][nt][0]; b1.u[1] = pk[1][nt][1];
        acco[1][vt] = MFMA16(av, b1.s, acco[1][vt]);
      }
    }
  }
  __builtin_amdgcn_s_setprio(0);

  // ---- epilogue: packed 8B stores (regular: 32B chunks need L2 merging —
  // NT here caused 2x HBM write amplification, r11 WRITE_SIZE 33->70MB) ----
  u16* obuf = (u16*)(ws + OFF_OBUF);
  const size_t orow0 = (size_t)win * WIN_SZ;
#pragma unroll
  for (int im = 0; im < 2; ++im) {
    if (im < nmt) {
      const int mt = (im == 0) ? mt0 : mt1;
      const int row = mt * 16 + cl;
      if (row < WIN_SZ) {
#pragma unroll
        for (int vt = 0; vt < 4; ++vt) {
          u16 ov[4];
#pragma unroll
          for (int r = 0; r < 4; ++r) ov[r] = f2bf(acco[im][vt][r]);
          *(uint2*)&obuf[(orow0 + row) * DM + h * KD + vt * 16 + q * 4] =
              *(const uint2*)ov;
        }
      }
    }
  }
}

// ---------------- GEMM: C[M,N] = A[M,512] @ Bt[N,512]^T + bias (fp32 out) ----------------
__global__ __launch_bounds__(256, 4)
void gemm_k(const u16* __restrict__ ws, unsigned aoff0, unsigned btoff,
            unsigned biasoff, float* __restrict__ Cout, int Ntot) {
  __shared__ u16 Alds[128 * 64];
  __shared__ u16 Blds[128 * 64];

  // XCD-locality mapping (T1): the 4 n-blocks sharing an A-panel get ids
  // differing by multiples of 8 (same XCD) and consecutive in that XCD's
  // stream -> the 131KB A-panel is read from HBM once, L2-hit 3x.
  // f = (p>>3)*32 + nb*8 + (p&7); panels padded to 264 (28 dummy blocks).
  const int f = blockIdx.x;
  const int nb = (f >> 3) & 3;
  const int p = ((f >> 5) << 3) + (f & 7);
  if (p >= MBLKS) return;

  const int t = threadIdx.x;
  const int w = t >> 6;
  const int l = t & 63;
  const int m0 = p * 128, n0 = nb * 128;
  const int lr = t >> 3;
  // same G4/T2 swizzle as qkvattn_k phase 1 (128B row stride)
  const int lsw = (((t & 7) ^ ((t >> 3) & 7)) * 8);

  unsigned aoff[4], boff[4];
#pragma unroll
  for (int i = 0; i < 4; ++i) {
    int m = m0 + i * 32 + lr;
    aoff[i] = (m < MROWS) ? (aoff0 + (unsigned)m * DM + lsw) : OFF_ZBLK;
    boff[i] = btoff + (unsigned)(n0 + i * 32 + lr) * DM + lsw;
  }

  f32x4 acc[4][4] = {};
  const int wm = (w & 1) * 64;
  const int wn = (w >> 1) * 64;
  const int q = l >> 4, cl = l & 15;

  for (int k0 = 0; k0 < DM; k0 += 64) {
    __syncthreads();
#pragma unroll
    for (int i = 0; i < 4; ++i) {
      gl2lds16(ws + aoff[i] + (aoff[i] == OFF_ZBLK ? 0u : (unsigned)k0),
               &Alds[(i * 32 + w * 8) * 64]);
      gl2lds16(ws + boff[i] + k0, &Blds[(i * 32 + w * 8) * 64]);
    }
    __syncthreads();
#pragma unroll
    for (int ks = 0; ks < 2; ++ks) {
      short8 av[4], bv_[4];
      const int ko = ks * 32 + q * 8;
      const int koS = ko ^ ((cl & 7) << 3);   // read-side swizzle
#pragma unroll
      for (int mi = 0; mi < 4; ++mi)
        av[mi] = *(const short8*)&Alds[(wm + mi * 16 + cl) * 64 + koS];
#pragma unroll
      for (int ni = 0; ni < 4; ++ni)
        bv_[ni] = *(const short8*)&Blds[(wn + ni * 16 + cl) * 64 + koS];
      __builtin_amdgcn_s_setprio(1);
#pragma unroll
      for (int mi = 0; mi < 4; ++mi)
#pragma unroll
        for (int ni = 0; ni < 4; ++ni)
          acc[mi][ni] = __builtin_amdgcn_mfma_f32_16x16x32_bf16(
              av[mi], bv_[ni], acc[mi][ni], 0, 0, 0);
      __builtin_amdgcn_s_setprio(0);
    }
  }

  const float* biasF = (const float*)(ws + biasoff);
#pragma unroll
  for (int mi = 0; mi < 4; ++mi) {
#pragma unroll
    for (int ni = 0; ni < 4; ++ni) {
      int col = n0 + wn + ni * 16 + cl;
      float bb = biasF[col];
#pragma unroll
      for (int r = 0; r < 4; ++r) {
        int row = m0 + wm + mi * 16 + q * 4 + r;
        if (row < MROWS)
          __builtin_nontemporal_store(acc[mi][ni][r] + bb,
                                      &Cout[(size_t)row * Ntot + col]);
      }
    }
  }
}

extern "C" void kernel_launch(void* const* d_in, const int* in_sizes, int n_in,
                              void* d_out, int out_size, void* d_ws, size_t ws_size,
                              hipStream_t stream) {
  const float* x  = (const float*)d_in[0];
  const float* Wq = (const float*)d_in[1];
  const float* bq = (const float*)d_in[2];
  const float* Wk = (const float*)d_in[3];
  const float* bk = (const float*)d_in[4];
  const float* Wv = (const float*)d_in[5];
  const float* bv = (const float*)d_in[6];
  const float* Wo = (const float*)d_in[7];
  const float* bo = (const float*)d_in[8];

  u16* ws = (u16*)d_ws;

  prepx_k<<<dim3(CONV_GRID + 256), dim3(256), 0, stream>>>(
      x, Wq, Wk, Wv, Wo, bq, bk, bv, bo, ws);
  qkvattn_k<<<dim3(NWINS * NHEAD), dim3(256), 0, stream>>>(ws);
  gemm_k<<<dim3(GEMM_BLKS), dim3(256), 0, stream>>>(
      ws, OFF_OBUF, OFF_WOT, OFF_BIAS2, (float*)d_out, DM);
}

// Round 13
// 233.415 us; speedup vs baseline: 1.4096x; 1.0257x over previous
//
#include <hip/hip_runtime.h>

typedef unsigned short u16;
typedef __attribute__((ext_vector_type(4))) float f32x4;
typedef __attribute__((ext_vector_type(8))) short short8;
typedef __attribute__((ext_vector_type(4))) short short4v;

#define WIN_SZ 100
#define NWIN 41
#define NBATCH 8
#define SEQ 4096
#define DM 512
#define NHEAD 8
#define KD 64
#define NWINS (NBATCH * NWIN)    // 328
#define MROWS (NWINS * WIN_SZ)   // 32800
#define MBLKS 257                // ceil(32800/128)
#define TOKPB (NWIN * WIN_SZ)    // 4100
#define NQKV 1536
#define CONV_GRID 2048                          // grid-stride conv blocks (G11)
#define GEMM_BLKS (((MBLKS + 7) / 8) * 32)      // 33 panel-groups * 32 = 1056

// ws layout (u16 element offsets)
#define OFF_XBF   0u
#define OFF_OBUF  16793600u                 // + MROWS*DM
#define OFF_WQKVT 33587200u                 // + MROWS*DM
#define OFF_WOT   34373632u                 // + NQKV*DM
#define OFF_ZBLK  34635776u                 // + DM*DM
#define OFF_BIAS  34636032u                 // + 256   (1536 fp32 qkv bias)
#define OFF_BIAS2 34639104u                 // + 3072  (512 fp32 bo)

// 16x16x16 bf16 MFMA (K=16): B-frag k-slice (l>>4)*4+e matches the in-register
// P layout after swapped-QK^T, so PV needs no cross-lane P redistribution.
// NOTE: no __has_builtin guard — it returns false in the HOST pass of hipcc
// (aux-target builtins are callable there but not listed), which broke r6/r7.
#define MFMA16(a, b, c) __builtin_amdgcn_mfma_f32_16x16x16bf16_1k(a, b, c, 0, 0, 0)

// hand-rolled RNE f32->bf16 (kept only for the cold prep-weights path)
__device__ __forceinline__ u16 f2bf(float f) {
  union { float f; unsigned i; } v; v.f = f;
  unsigned r = (v.i + 0x7fffu + ((v.i >> 16) & 1u)) >> 16;
  return (u16)r;
}

// HW paired f32->bf16 (RNE): 1 instruction for 2 values. No builtin on gfx950
// (T12 / m240) — inline asm. Replaces the 4-op bit-twiddle in all hot paths
// (r12 counters: VALUBusy 38% > MfmaUtil 35%; ~690 of ~1300 VALU insts/thread
// were conversion).
__device__ __forceinline__ unsigned cvt_pk_bf16(float a, float b) {
  unsigned r;
  asm("v_cvt_pk_bf16_f32 %0, %1, %2" : "=v"(r) : "v"(a), "v"(b));
  return r;
}

// raw v_exp_f32 (exp2); softmax runs in log2 domain so the per-exp ln2 mul
// disappears (folded into the score scale constant).
__device__ __forceinline__ float exp2_fast(float x) {
  float r;
  asm("v_exp_f32 %0, %1" : "=v"(r) : "v"(x));
  return r;
}

// async global->LDS, 16B per lane; lds base wave-uniform (HW adds lane*16)
__device__ __forceinline__ void gl2lds16(const void* g, void* lds) {
  __builtin_amdgcn_global_load_lds(
      (const __attribute__((address_space(1))) void*)g,
      (__attribute__((address_space(3))) void*)lds, 16, 0, 0);
}

// ---------- merged: x fp32->bf16 window gather (blocks [0,CONV_GRID)) ----------
// ---------- + weight transposes / biases / zblk (blocks [CONV_GRID, +256)) ----
__global__ void prepx_k(const float* __restrict__ x,
                        const float* __restrict__ Wq, const float* __restrict__ Wk,
                        const float* __restrict__ Wv, const float* __restrict__ Wo,
                        const float* __restrict__ bq, const float* __restrict__ bk,
                        const float* __restrict__ bv, const float* __restrict__ bo,
                        u16* __restrict__ ws) {
  __shared__ u16 tile[64][65];
  const int t = threadIdx.x;
  if (blockIdx.x < CONV_GRID) {
    // ---- convx half: grid-stride, 32B in / 16B out per thread-iter ----
    // NT loads: x is read exactly once; keep L2 for xbf (re-read by qkvattn).
    u16* xbf = ws + OFF_XBF;
    const int total = MROWS * 64;               // 32B-group count
    for (int i = blockIdx.x * 256 + t; i < total; i += CONV_GRID * 256) {
      int m = i >> 6;
      int c8 = (i & 63) * 8;
      int b = m / TOKPB, tk = m - b * TOKPB;
      uint4 ov = make_uint4(0u, 0u, 0u, 0u);
      if (tk < SEQ) {
        const float* src = x + (size_t)(b * SEQ + tk) * DM + c8;
        f32x4 v0 = __builtin_nontemporal_load((const f32x4*)src);
        f32x4 v1 = __builtin_nontemporal_load((const f32x4*)(src + 4));
        ov.x = cvt_pk_bf16(v0.x, v0.y);
        ov.y = cvt_pk_bf16(v0.z, v0.w);
        ov.z = cvt_pk_bf16(v1.x, v1.y);
        ov.w = cvt_pk_bf16(v1.z, v1.w);
      }
      *(uint4*)(xbf + (size_t)m * DM + c8) = ov;
    }
    return;
  }
  // ---- prep half: p -> (bx, by, z) of the old dim3(8,8,4) grid ----
  const int p = blockIdx.x - CONV_GRID;
  const int z = p >> 6, by = (p >> 3) & 7, bx = p & 7;
  const float* src = (z == 0) ? Wq : (z == 1) ? Wk : (z == 2) ? Wv : Wo;
  u16* dst = (z < 3) ? (ws + OFF_WQKVT + (unsigned)z * 512u * 512u)
                     : (ws + OFF_WOT);
  const int k0 = by * 64, n0 = bx * 64;
  const int c = t & 63, r4 = t >> 6;
#pragma unroll
  for (int pp = 0; pp < 16; ++pp) {
    int r = pp * 4 + r4;
    tile[r][c] = f2bf(src[(size_t)(k0 + r) * 512 + n0 + c]);
  }
  __syncthreads();
#pragma unroll
  for (int pp = 0; pp < 16; ++pp) {
    int r = pp * 4 + r4;                       // n index within tile
    dst[(size_t)(n0 + r) * 512 + k0 + c] = tile[c][r];
  }
  if (bx == 0 && by == 0) {
    float* biasF = (float*)(ws + OFF_BIAS);
    float* biasO = (float*)(ws + OFF_BIAS2);
    for (int j = t; j < 512; j += 256) {
      if (z == 0) biasF[j] = bq[j];
      else if (z == 1) biasF[512 + j] = bk[j];
      else if (z == 2) biasF[1024 + j] = bv[j];
      else biasO[j] = bo[j];
    }
    if (z == 3 && t < 128) ws[OFF_ZBLK + t] = 0;
  }
}

// -------------- fused QKV projection + attention, one block per (win, head) --------------
#define QKS 72   // Qs/Ks stride
#define PS 136   // Vt stride
// LDS phase-union (u16 elems), total 24832 (49664 B -> 3 blocks/CU):
//   phase1 (staging, dies at post-loop barrier): Xs [0,7168) + Wsl [7168,19456)
//   phase2+: Vt [0,8704) | Qs [8704,16768) | Ks [16768,24832)
//   (no P buffer: softmax->PV stays in registers via swapped QK^T + K=16 PV)
#define SM_ELEMS 24832

__global__ __launch_bounds__(256, 3)
void qkvattn_k(const u16* __restrict__ ws) {
  __shared__ u16 smem[SM_ELEMS];
  u16* Xs  = smem;              // 112 x 64 (column-slot XOR-swizzled per row)
  u16* Wsl = smem + 7168;       // 192 x 64 (column-slot XOR-swizzled per row)
  u16* Vt  = smem;              // 64 x 136
  u16* Qs  = smem + 8704;       // 112 x 72
  u16* Ks  = smem + 16768;      // 112 x 72

  // XCD-locality mapping (T1): all 8 heads of a window share f mod 8 (same
  // XCD L2) and are consecutive in that XCD's stream -> X tile staged 8x
  // while L2-hot. f = (win>>3)*64 + h*8 + (win&7); bijective over 2624.
  const int f = blockIdx.x;
  const int h = (f >> 3) & 7;
  const int win = ((f >> 6) << 3) + (f & 7);

  const int t = threadIdx.x, w = t >> 6, l = t & 63;
  const int q = l >> 4, cl = l & 15;
  // Bank-conflict fix (G4/T2, m173 pattern): pre-swizzle the GLOBAL source
  // column; read-side XOR undoes it. 128B row stride otherwise 16-way conflicts.
  const int lsw = (((t & 7) ^ ((t >> 3) & 7)) * 8);

  // staging source offsets (column pre-swizzled)
  unsigned xoff[4];
#pragma unroll
  for (int i = 0; i < 4; ++i) {
    int m = i * 32 + (t >> 3);
    xoff[i] = (m < WIN_SZ)
                  ? (OFF_XBF + (unsigned)(win * WIN_SZ + m) * DM + lsw)
                  : OFF_ZBLK;
  }
  unsigned woff[6];
#pragma unroll
  for (int i = 0; i < 6; ++i) {
    int g = i * 32 + (t >> 3);
    unsigned nrow = (unsigned)(g >> 6) * 512u + (unsigned)h * 64u + (g & 63);
    woff[i] = OFF_WQKVT + nrow * DM + lsw;
  }

  // ---- phase 1: QKV projection. wave w owns n-tiles {3w,3w+1,3w+2} of 12 ----
  f32x4 acc_p[7][3] = {};
  for (int k0 = 0; k0 < DM; k0 += 64) {
    __syncthreads();
#pragma unroll
    for (int i = 0; i < 4; ++i)
      if (i * 32 + w * 8 < 112)   // wave-uniform
        gl2lds16(ws + xoff[i] + (xoff[i] == OFF_ZBLK ? 0u : (unsigned)k0),
                 &Xs[(i * 32 + w * 8) * 64]);
#pragma unroll
    for (int i = 0; i < 6; ++i)
      gl2lds16(ws + woff[i] + k0, &Wsl[(i * 32 + w * 8) * 64]);
    __syncthreads();
#pragma unroll
    for (int ks = 0; ks < 2; ++ks) {
      const int ko = ks * 32 + q * 8;
      const int koS = ko ^ ((cl & 7) << 3);   // read-side swizzle
      short8 af[7], bf[3];
#pragma unroll
      for (int mt = 0; mt < 7; ++mt)
        af[mt] = *(const short8*)&Xs[(mt * 16 + cl) * 64 + koS];
#pragma unroll
      for (int ntl = 0; ntl < 3; ++ntl)
        bf[ntl] = *(const short8*)&Wsl[((3 * w + ntl) * 16 + cl) * 64 + koS];
      __builtin_amdgcn_s_setprio(1);
#pragma unroll
      for (int mt = 0; mt < 7; ++mt)
#pragma unroll
        for (int ntl = 0; ntl < 3; ++ntl)
          acc_p[mt][ntl] = __builtin_amdgcn_mfma_f32_16x16x32_bf16(
              af[mt], bf[ntl], acc_p[mt][ntl], 0, 0, 0);
      __builtin_amdgcn_s_setprio(0);
    }
  }
  __syncthreads();  // staging reads drained; Vt/Qs/Ks may now overwrite

  // ---- phase 2: accs (+bias) -> Qs / Ks / Vt (paired HW cvt) ----
  {
    const float* biasF = (const float*)(ws + OFF_BIAS);
#pragma unroll
    for (int ntl = 0; ntl < 3; ++ntl) {
      const int nt = 3 * w + ntl;                      // wave-uniform
      const int cw = (nt & 3) * 16 + cl;               // col within Q/K/V
      const float bb = biasF[(nt >> 2) * 512 + h * 64 + cw];
      if (nt < 8) {
        u16* dst = (nt < 4) ? Qs : Ks;
#pragma unroll
        for (int mt = 0; mt < 7; ++mt) {
          const int tok = mt * 16 + q * 4;
          unsigned p01 = cvt_pk_bf16(acc_p[mt][ntl][0] + bb, acc_p[mt][ntl][1] + bb);
          unsigned p23 = cvt_pk_bf16(acc_p[mt][ntl][2] + bb, acc_p[mt][ntl][3] + bb);
          dst[(tok + 0) * QKS + cw] = (u16)p01;
          dst[(tok + 1) * QKS + cw] = (u16)(p01 >> 16);
          dst[(tok + 2) * QKS + cw] = (u16)p23;
          dst[(tok + 3) * QKS + cw] = (u16)(p23 >> 16);
        }
      } else {
        // V: r-index is contiguous in Vt -> 2 cvt_pk feed one b64 write
#pragma unroll
        for (int mt = 0; mt < 7; ++mt) {
          uint2 pv;
          pv.x = cvt_pk_bf16(acc_p[mt][ntl][0] + bb, acc_p[mt][ntl][1] + bb);
          pv.y = cvt_pk_bf16(acc_p[mt][ntl][2] + bb, acc_p[mt][ntl][3] + bb);
          *(uint2*)&Vt[cw * PS + mt * 16 + q * 4] = pv;
        }
      }
    }
    // no Vt pad zeroing needed: PV only reads tokens 0..111 (K=16 tiles),
    // and tokens 100..111 are killed by P=0 from the softmax mask.
  }
  __syncthreads();

  // ---- phase 3: S^T = K Q^T (swapped operands). wave w owns Q-tiles {w, w+4} ----
  // D layout: row = token = nt*16 + q*4 + r (A=K side), col = Q-row = mt*16 + cl.
  const int nmt = (w < 3) ? 2 : 1;
  const int mt0 = w, mt1 = w + 4;

  f32x4 accs[2][7];
#pragma unroll
  for (int im = 0; im < 2; ++im) {
    if (im < nmt) {
      const int mt = (im == 0) ? mt0 : mt1;
      const int ar = (mt * 16 + cl) * QKS + q * 8;
      short8 qa0 = *(const short8*)&Qs[ar];
      short8 qa1 = *(const short8*)&Qs[ar + 32];
      __builtin_amdgcn_s_setprio(1);
#pragma unroll
      for (int nt = 0; nt < 7; ++nt) {
        const int br = (nt * 16 + cl) * QKS + q * 8;
        short8 kb0 = *(const short8*)&Ks[br];
        short8 kb1 = *(const short8*)&Ks[br + 32];
        f32x4 c = {};
        c = __builtin_amdgcn_mfma_f32_16x16x32_bf16(kb0, qa0, c, 0, 0, 0);
        c = __builtin_amdgcn_mfma_f32_16x16x32_bf16(kb1, qa1, c, 0, 0, 0);
        accs[im][nt] = c;
      }
      __builtin_amdgcn_s_setprio(0);
    }
  }

  // softmax in log2 domain (scale' = 1/sqrt(64) * log2(e); exp2 = raw
  // v_exp_f32, no per-exp ln2 mul). In-lane 28 values + 2 shfl over q-group;
  // P packed to bf16 pairs via cvt_pk: pk[im][nt][j] holds tokens
  // nt*16 + 4q + {2j, 2j+1} -- exactly the 16x16x16 B-frag k-slice.
  const float scale2 = 0.18033688011112042f;  // 0.125 * log2(e)
  unsigned pk[2][7][2];
#pragma unroll
  for (int im = 0; im < 2; ++im) {
    if (im < nmt) {
      float mx = -1e30f;
#pragma unroll
      for (int nt = 0; nt < 7; ++nt)
#pragma unroll
        for (int r = 0; r < 4; ++r) {
          float s = accs[im][nt][r] * scale2;
          accs[im][nt][r] = s;
          if ((nt < 6) || (q == 0)) mx = fmaxf(mx, s);   // token<100 valid
        }
      mx = fmaxf(mx, __shfl_xor(mx, 16, 64));
      mx = fmaxf(mx, __shfl_xor(mx, 32, 64));
      float sum = 0.f;
#pragma unroll
      for (int nt = 0; nt < 7; ++nt)
#pragma unroll
        for (int r = 0; r < 4; ++r) {
          bool valid = (nt < 6) || (q == 0);
          float e = valid ? exp2_fast(accs[im][nt][r] - mx) : 0.f;
          accs[im][nt][r] = e;
          sum += e;
        }
      sum += __shfl_xor(sum, 16, 64);
      sum += __shfl_xor(sum, 32, 64);
      float inv = 1.0f / sum;
#pragma unroll
      for (int nt = 0; nt < 7; ++nt) {
        pk[im][nt][0] = cvt_pk_bf16(accs[im][nt][0] * inv, accs[im][nt][1] * inv);
        pk[im][nt][1] = cvt_pk_bf16(accs[im][nt][2] * inv, accs[im][nt][3] * inv);
      }
    }
  }
  // no barrier needed: PV reads only Vt (written before the phase-2 barrier)

  // ---- phase 4: O^T = V^T P^T via K=16 MFMA, P straight from registers ----
  // D: col = Q-row = mt*16+cl, row = kd = vt*16 + q*4 + r.
  f32x4 acco[2][4] = {};
  __builtin_amdgcn_s_setprio(1);
#pragma unroll
  for (int vt = 0; vt < 4; ++vt) {
#pragma unroll
    for (int nt = 0; nt < 7; ++nt) {
      short4v av = *(const short4v*)&Vt[(vt * 16 + cl) * PS + nt * 16 + q * 4];
      union { unsigned u[2]; short4v s; } b0, b1;
      b0.u[0] = pk[0][nt][0]; b0.u[1] = pk[0][nt][1];
      acco[0][vt] = MFMA16(av, b0.s, acco[0][vt]);
      if (nmt == 2) {
        b1.u[0] = pk[1][nt][0]; b1.u[1] = pk[1][nt][1];
        acco[1][vt] = MFMA16(av, b1.s, acco[1][vt]);
      }
    }
  }
  __builtin_amdgcn_s_setprio(0);

  // ---- epilogue: packed 8B stores (regular: 32B chunks need L2 merging —
  // NT here caused 2x HBM write amplification, r11 WRITE_SIZE 33->70MB) ----
  u16* obuf = (u16*)(ws + OFF_OBUF);
  const size_t orow0 = (size_t)win * WIN_SZ;
#pragma unroll
  for (int im = 0; im < 2; ++im) {
    if (im < nmt) {
      const int mt = (im == 0) ? mt0 : mt1;
      const int row = mt * 16 + cl;
      if (row < WIN_SZ) {
#pragma unroll
        for (int vt = 0; vt < 4; ++vt) {
          uint2 ov;
          ov.x = cvt_pk_bf16(acco[im][vt][0], acco[im][vt][1]);
          ov.y = cvt_pk_bf16(acco[im][vt][2], acco[im][vt][3]);
          *(uint2*)&obuf[(orow0 + row) * DM + h * KD + vt * 16 + q * 4] = ov;
        }
      }
    }
  }
}

// ---------------- GEMM: C[M,N] = A[M,512] @ Bt[N,512]^T + bias (fp32 out) ----------------
__global__ __launch_bounds__(256, 4)
void gemm_k(const u16* __restrict__ ws, unsigned aoff0, unsigned btoff,
            unsigned biasoff, float* __restrict__ Cout, int Ntot) {
  __shared__ u16 Alds[128 * 64];
  __shared__ u16 Blds[128 * 64];

  // XCD-locality mapping (T1): the 4 n-blocks sharing an A-panel get ids
  // differing by multiples of 8 (same XCD) and consecutive in that XCD's
  // stream -> the 131KB A-panel is read from HBM once, L2-hit 3x.
  // f = (p>>3)*32 + nb*8 + (p&7); panels padded to 264 (28 dummy blocks).
  const int f = blockIdx.x;
  const int nb = (f >> 3) & 3;
  const int p = ((f >> 5) << 3) + (f & 7);
  if (p >= MBLKS) return;

  const int t = threadIdx.x;
  const int w = t >> 6;
  const int l = t & 63;
  const int m0 = p * 128, n0 = nb * 128;
  const int lr = t >> 3;
  // same G4/T2 swizzle as qkvattn_k phase 1 (128B row stride)
  const int lsw = (((t & 7) ^ ((t >> 3) & 7)) * 8);

  unsigned aoff[4], boff[4];
#pragma unroll
  for (int i = 0; i < 4; ++i) {
    int m = m0 + i * 32 + lr;
    aoff[i] = (m < MROWS) ? (aoff0 + (unsigned)m * DM + lsw) : OFF_ZBLK;
    boff[i] = btoff + (unsigned)(n0 + i * 32 + lr) * DM + lsw;
  }

  f32x4 acc[4][4] = {};
  const int wm = (w & 1) * 64;
  const int wn = (w >> 1) * 64;
  const int q = l >> 4, cl = l & 15;

  for (int k0 = 0; k0 < DM; k0 += 64) {
    __syncthreads();
#pragma unroll
    for (int i = 0; i < 4; ++i) {
      gl2lds16(ws + aoff[i] + (aoff[i] == OFF_ZBLK ? 0u : (unsigned)k0),
               &Alds[(i * 32 + w * 8) * 64]);
      gl2lds16(ws + boff[i] + k0, &Blds[(i * 32 + w * 8) * 64]);
    }
    __syncthreads();
#pragma unroll
    for (int ks = 0; ks < 2; ++ks) {
      short8 av[4], bv_[4];
      const int ko = ks * 32 + q * 8;
      const int koS = ko ^ ((cl & 7) << 3);   // read-side swizzle
#pragma unroll
      for (int mi = 0; mi < 4; ++mi)
        av[mi] = *(const short8*)&Alds[(wm + mi * 16 + cl) * 64 + koS];
#pragma unroll
      for (int ni = 0; ni < 4; ++ni)
        bv_[ni] = *(const short8*)&Blds[(wn + ni * 16 + cl) * 64 + koS];
      __builtin_amdgcn_s_setprio(1);
#pragma unroll
      for (int mi = 0; mi < 4; ++mi)
#pragma unroll
        for (int ni = 0; ni < 4; ++ni)
          acc[mi][ni] = __builtin_amdgcn_mfma_f32_16x16x32_bf16(
              av[mi], bv_[ni], acc[mi][ni], 0, 0, 0);
      __builtin_amdgcn_s_setprio(0);
    }
  }

  const float* biasF = (const float*)(ws + biasoff);
#pragma unroll
  for (int mi = 0; mi < 4; ++mi) {
#pragma unroll
    for (int ni = 0; ni < 4; ++ni) {
      int col = n0 + wn + ni * 16 + cl;
      float bb = biasF[col];
#pragma unroll
      for (int r = 0; r < 4; ++r) {
        int row = m0 + wm + mi * 16 + q * 4 + r;
        if (row < MROWS)
          __builtin_nontemporal_store(acc[mi][ni][r] + bb,
                                      &Cout[(size_t)row * Ntot + col]);
      }
    }
  }
}

extern "C" void kernel_launch(void* const* d_in, const int* in_sizes, int n_in,
                              void* d_out, int out_size, void* d_ws, size_t ws_size,
                              hipStream_t stream) {
  const float* x  = (const float*)d_in[0];
  const float* Wq = (const float*)d_in[1];
  const float* bq = (const float*)d_in[2];
  const float* Wk = (const float*)d_in[3];
  const float* bk = (const float*)d_in[4];
  const float* Wv = (const float*)d_in[5];
  const float* bv = (const float*)d_in[6];
  const float* Wo = (const float*)d_in[7];
  const float* bo = (const float*)d_in[8];

  u16* ws = (u16*)d_ws;

  prepx_k<<<dim3(CONV_GRID + 256), dim3(256), 0, stream>>>(
      x, Wq, Wk, Wv, Wo, bq, bk, bv, bo, ws);
  qkvattn_k<<<dim3(NWINS * NHEAD), dim3(256), 0, stream>>>(ws);
  gemm_k<<<dim3(GEMM_BLKS), dim3(256), 0, stream>>>(
      ws, OFF_OBUF, OFF_WOT, OFF_BIAS2, (float*)d_out, DM);
}